// Round 1
// baseline (6706.861 us; speedup 1.0000x reference)
//
#include <hip/hip_runtime.h>
#include <math.h>

// ---------------- problem constants ----------------
#define Bz     64
#define LENS   128
#define LENP   12
#define Tz     140
#define Dz     768
#define NHz    12
#define HDz    64
#define NLz    6
#define DMLPz  3072
#define NCLSz  10
#define EPBz   278                 // edges per batch = 2*(T-1)
#define NTOKz  (Bz*Tz)             // 8960
#define ZDIMz  (Tz*Dz)             // 107520
#define KBIGz  (LENS*Dz)           // 98304
#define KSMALLz (LENP*Dz)          // 9216

typedef float f32x4 __attribute__((ext_vector_type(4)));
typedef unsigned int u32x4 __attribute__((ext_vector_type(4)));

__device__ __forceinline__ float wave_sum(float v){
  #pragma unroll
  for (int m = 32; m; m >>= 1) v += __shfl_xor(v, m);
  return v;
}
__device__ __forceinline__ float wave_max(float v){
  #pragma unroll
  for (int m = 32; m; m >>= 1) v = fmaxf(v, __shfl_xor(v, m));
  return v;
}
__device__ __forceinline__ float gelu_tanh(float u){
  float c = 0.7978845608028654f * (u + 0.044715f * u * u * u);
  return 0.5f * u * (1.0f + tanhf(c));
}
__device__ __forceinline__ float gelu_exact(float u){
  return 0.5f * u * (1.0f + erff(u * 0.7071067811865476f));
}

// float -> bf16 (RNE) and back, branchless manual (m240: scalar cast path is fine,
// manual keeps it compiler-version-independent)
__device__ __forceinline__ unsigned int f2bf(float x){
  unsigned int u = __float_as_uint(x);
  return (u + 0x7fffu + ((u >> 16) & 1u)) >> 16;
}
__device__ __forceinline__ float bf2f(unsigned int h){
  return __uint_as_float(h << 16);
}

// v_mfma_f32_16x16x32_bf16 via inline asm (operand types are just register tuples)
__device__ __forceinline__ f32x4 mfma_bf16(u32x4 a, u32x4 b, f32x4 c){
  asm("v_mfma_f32_16x16x32_bf16 %0, %1, %2, %0" : "+v"(c) : "v"(a), "v"(b));
  return c;
}

// ---------------- positional encoding (once) ----------------
__global__ void k_pe(float* pe){
  int idx = blockIdx.x * 256 + threadIdx.x;      // < 128*768
  int s = idx / Dz, o = idx % Dz;
  int ie = o & ~1;
  double ang = (double)s * pow(10000.0, -(double)ie / (double)Dz);
  pe[idx] = (o & 1) ? (float)cos(ang) : (float)sin(ang);
}

// transpose conv_w (768,48,3) -> cwt[(k*48+i)*768 + o]
__global__ void k_cwt(const float* __restrict__ cw, float* __restrict__ cwt){
  int idx = blockIdx.x * 256 + threadIdx.x;      // < 144*768
  int o = idx % Dz, j = idx / Dz;                // j = k*48+i
  int i = j % 48, k = j / 48;
  cwt[j * Dz + o] = cw[o * 144 + i * 3 + k];
}

// conv encoder: one block per (b,s); h0[b,s,:] = conv + PE
__global__ __launch_bounds__(256) void k_conv(const float* __restrict__ x_enc,
                                              const float* __restrict__ cwt,
                                              const float* __restrict__ pe,
                                              float* __restrict__ h0){
  int b = blockIdx.x / LENS, s = blockIdx.x % LENS;
  int tid = threadIdx.x;
  __shared__ float in144[144];
  if (tid < 144){
    int k = tid / 48, i = tid % 48;
    int sp = (s + k - 1 + LENS) % LENS;          // circular-padded inp column
    int p = i / 3, m = i % 3;
    int j = sp * 8 + p; if (j > 1023) j = 1023;  // repeat last timestep
    in144[tid] = x_enc[(b * 1024 + j) * 3 + m];
  }
  __syncthreads();
  for (int o = tid; o < Dz; o += 256){
    float acc = pe[s * Dz + o];
    #pragma unroll 8
    for (int j = 0; j < 144; ++j) acc += in144[j] * cwt[j * Dz + o];
    h0[((size_t)(b * Tz + s)) * Dz + o] = acc;
  }
}

__global__ void k_prompt(const float* __restrict__ pr, float* __restrict__ h0){
  int idx = blockIdx.x * 256 + threadIdx.x;      // < 64*12*768
  int b = idx / (LENP * Dz), r = idx % (LENP * Dz);
  h0[((size_t)(b * Tz + LENS)) * Dz + r] = pr[r];
}

// node L2 norms (one wave per node)
__global__ void k_norms(const float* __restrict__ h0, float* __restrict__ nrm){
  int n = blockIdx.x, lane = threadIdx.x;
  const float* r = h0 + (size_t)n * Dz;
  float s = 0.f;
  for (int d = lane; d < Dz; d += 64){ float v = r[d]; s += v * v; }
  s = wave_sum(s);
  if (lane == 0) nrm[n] = sqrtf(s);
}

// per-edge cosine (one wave per edge)
__global__ void k_ecos(const float* __restrict__ h0, const int* __restrict__ eidx,
                       const float* __restrict__ nrm, float* __restrict__ cosb){
  int e = blockIdx.x, lane = threadIdx.x;
  int sN = eidx[e], dN = eidx[Bz * EPBz + e];
  const float* a = h0 + (size_t)sN * Dz;
  const float* b = h0 + (size_t)dN * Dz;
  float s = 0.f;
  for (int d = lane; d < Dz; d += 64) s += a[d] * b[d];
  s = wave_sum(s);
  if (lane == 0) cosb[e] = s / (nrm[sN] * nrm[dN] + 1e-8f);
}

// segment softmax (2 segments per batch), one block per batch
__global__ __launch_bounds__(256) void k_esoft(const float* __restrict__ cosb,
                                               const int* __restrict__ eseg,
                                               float* __restrict__ ew){
  int b = blockIdx.x, tid = threadIdx.x;
  __shared__ float c[EPBz];
  __shared__ unsigned char gg[EPBz];
  __shared__ float r0[256], r1[256];
  for (int e = tid; e < EPBz; e += 256){
    c[e] = cosb[b * EPBz + e];
    gg[e] = (unsigned char)(eseg[b * EPBz + e] - 2 * b);
  }
  __syncthreads();
  float m0 = -1e30f, m1 = -1e30f;
  for (int e = tid; e < EPBz; e += 256){
    if (gg[e]) m1 = fmaxf(m1, c[e]); else m0 = fmaxf(m0, c[e]);
  }
  r0[tid] = m0; r1[tid] = m1; __syncthreads();
  for (int s = 128; s; s >>= 1){
    if (tid < s){ r0[tid] = fmaxf(r0[tid], r0[tid+s]); r1[tid] = fmaxf(r1[tid], r1[tid+s]); }
    __syncthreads();
  }
  m0 = r0[0]; m1 = r1[0]; __syncthreads();
  float s0 = 0.f, s1 = 0.f;
  for (int e = tid; e < EPBz; e += 256){
    float ex = expf(c[e] - (gg[e] ? m1 : m0));
    c[e] = ex;
    if (gg[e]) s1 += ex; else s0 += ex;
  }
  r0[tid] = s0; r1[tid] = s1; __syncthreads();
  for (int s = 128; s; s >>= 1){
    if (tid < s){ r0[tid] += r0[tid+s]; r1[tid] += r1[tid+s]; }
    __syncthreads();
  }
  s0 = r0[0]; s1 = r1[0];
  for (int e = tid; e < EPBz; e += 256)
    ew[b * EPBz + e] = c[e] / ((gg[e] ? s1 : s0) + 1e-8f);
}

// s init with both biases
__global__ void k_fills(const float* __restrict__ b1, const float* __restrict__ b0,
                        float* __restrict__ sbuf){
  int idx = blockIdx.x * 256 + threadIdx.x;      // < 64*768
  int d = idx % Dz;
  sbuf[idx] = b1[d] + b0[d];
}

// split-K GEMM: C(64x768) += A(64 x K) @ W(K x 768); A rows stride ZDIM in h0
__global__ __launch_bounds__(256) void k_splitk(const float* __restrict__ Abase, int aOff,
                                                const float* __restrict__ W,
                                                float* __restrict__ Cacc,
                                                int K, int kChunk){
  __shared__ __align__(16) float As[16 * 65];
  __shared__ __align__(16) float Ws[16 * 64];
  int tid = threadIdx.x, tx = tid % 16, ty = tid / 16;
  int n0 = blockIdx.x * 64;
  int kb = blockIdx.y * kChunk;
  int ke = kb + kChunk; if (ke > K) ke = K;
  float acc[16];
  #pragma unroll
  for (int i = 0; i < 16; ++i) acc[i] = 0.f;
  for (int kk = kb; kk < ke; kk += 16){
    #pragma unroll
    for (int r = 0; r < 4; ++r){
      int idx = tid + r * 256; int k = idx & 15, m = idx >> 4;   // m in [0,64)
      As[k * 65 + m] = Abase[(size_t)m * ZDIMz + aOff + kk + k];
    }
    #pragma unroll
    for (int r = 0; r < 4; ++r){
      int idx = tid + r * 256; int n = idx & 63, k = idx >> 6;
      Ws[k * 64 + n] = W[(size_t)(kk + k) * Dz + n0 + n];
    }
    __syncthreads();
    #pragma unroll
    for (int k = 0; k < 16; ++k){
      float a[4], bvv[4];
      #pragma unroll
      for (int i = 0; i < 4; ++i) a[i] = As[k * 65 + ty * 4 + i];
      #pragma unroll
      for (int j = 0; j < 4; ++j) bvv[j] = Ws[k * 64 + tx * 4 + j];
      #pragma unroll
      for (int i = 0; i < 4; ++i)
        #pragma unroll
        for (int j = 0; j < 4; ++j) acc[i * 4 + j] += a[i] * bvv[j];
    }
    __syncthreads();
  }
  #pragma unroll
  for (int i = 0; i < 4; ++i)
    #pragma unroll
    for (int j = 0; j < 4; ++j)
      atomicAdd(&Cacc[(size_t)(ty * 4 + i) * Dz + n0 + tx * 4 + j], acc[i * 4 + j]);
}

// P[b,d] = sum_{c<128} s[b,c]*l2s_w[c,d]
__global__ void k_psmall(const float* __restrict__ sbuf, const float* __restrict__ l2sw,
                         float* __restrict__ P){
  int idx = blockIdx.x * 256 + threadIdx.x;      // < 64*768
  int b = idx / Dz, d = idx % Dz;
  float acc = 0.f;
  #pragma unroll 8
  for (int c = 0; c < 128; ++c) acc += sbuf[b * Dz + c] * l2sw[c * Dz + d];
  P[idx] = acc;
}

__global__ void k_addwpe(const float* __restrict__ h0, const float* __restrict__ wpe,
                         float* __restrict__ h){
  size_t idx = (size_t)blockIdx.x * 256 + threadIdx.x;   // < NTOK*D
  int n = (int)(idx / Dz), d = (int)(idx % Dz);
  int t = n % Tz;
  h[idx] = h0[idx] + wpe[t * Dz + d];
}

// row layernorm over D=768, block per row (3 elems per thread)
__global__ __launch_bounds__(256) void k_ln(const float* __restrict__ in, float* __restrict__ out,
                                            const float* __restrict__ g, const float* __restrict__ bb){
  int row = blockIdx.x, tid = threadIdx.x;
  const float* r = in + (size_t)row * Dz;
  float v0 = r[tid], v1 = r[tid + 256], v2 = r[tid + 512];
  __shared__ float red[256];
  red[tid] = v0 + v1 + v2; __syncthreads();
  for (int s = 128; s; s >>= 1){ if (tid < s) red[tid] += red[tid + s]; __syncthreads(); }
  float mu = red[0] * (1.0f / Dz); __syncthreads();
  float d0 = v0 - mu, d1 = v1 - mu, d2 = v2 - mu;
  red[tid] = d0 * d0 + d1 * d1 + d2 * d2; __syncthreads();
  for (int s = 128; s; s >>= 1){ if (tid < s) red[tid] += red[tid + s]; __syncthreads(); }
  float rstd = rsqrtf(red[0] * (1.0f / Dz) + 1e-5f);
  float* o = out + (size_t)row * Dz;
  o[tid]       = d0 * rstd * g[tid]       + bb[tid];
  o[tid + 256] = d1 * rstd * g[tid + 256] + bb[tid + 256];
  o[tid + 512] = d2 * rstd * g[tid + 512] + bb[tid + 512];
}

// ---------------------------------------------------------------------------
// weight transpose+split kernel: W[K][N] fp32 -> WT[N][K/8 groups][8 hi|8 lo] bf16
// K,N multiples of 64. grid (N/64, K/64), 256 threads.
// ---------------------------------------------------------------------------
__global__ __launch_bounds__(256) void k_wt(const float* __restrict__ W,
                                            unsigned short* __restrict__ WT,
                                            int K, int N){
  __shared__ float T[64][65];
  int k0 = blockIdx.y * 64, n0v = blockIdx.x * 64;
  int tid = threadIdx.x;
  int tx = tid & 15, ty = tid >> 4;
  #pragma unroll
  for (int rr = 0; rr < 4; ++rr){
    int row = rr * 16 + ty;
    const float* src = &W[(size_t)(k0 + row) * N + n0v + tx * 4];
    f32x4 v = *(const f32x4*)src;
    T[row][tx * 4]     = v[0];
    T[row][tx * 4 + 1] = v[1];
    T[row][tx * 4 + 2] = v[2];
    T[row][tx * 4 + 3] = v[3];
  }
  __syncthreads();
  #pragma unroll
  for (int s = 0; s < 2; ++s){
    int gi = tid + s * 256;                      // 0..511  (64 n  x 8 k-groups)
    int n = gi >> 3, kg = gi & 7;
    unsigned int h[8], l[8];
    #pragma unroll
    for (int j = 0; j < 8; ++j){
      float x = T[kg * 8 + j][n];
      h[j] = f2bf(x);
      l[j] = f2bf(x - bf2f(h[j]));
    }
    u32x4 hv, lv;
    hv[0] = h[0] | (h[1] << 16); hv[1] = h[2] | (h[3] << 16);
    hv[2] = h[4] | (h[5] << 16); hv[3] = h[6] | (h[7] << 16);
    lv[0] = l[0] | (l[1] << 16); lv[1] = l[2] | (l[3] << 16);
    lv[2] = l[4] | (l[5] << 16); lv[3] = l[6] | (l[7] << 16);
    size_t base = (size_t)(n0v + n) * 2 * K + (size_t)(k0 / 8 + kg) * 16;
    *(u32x4*)&WT[base]     = hv;
    *(u32x4*)&WT[base + 8] = lv;
  }
}

// ---------------------------------------------------------------------------
// bf16x2-split MFMA GEMM: C = A(MxK fp32) @ W(KxN) with W pre-split in WT.
// 128x128 block tile, 4 waves of 64x64, BK=32, XOR-swizzled LDS (T2).
// Each operand element = hi + lo bf16; D = Ah*Bh + Ah*Bl + Al*Bh (fp32 acc).
// MODE 0: C = A@W + bias
// MODE 1: C = R + A@W + bias
// MODE 2: C = gelu_tanh(A@W + bias)
// MODE 3: C = R + A@W + bias + w_l2s*c_t*(lscale*P[b,col] + l2sb[col])
// ---------------------------------------------------------------------------
template<int MODE>
__global__ __launch_bounds__(256, 2) void k_bgemm(const float* __restrict__ A,
                                                  const unsigned short* __restrict__ WT,
                                                  const float* __restrict__ bias,
                                                  const float* __restrict__ R,
                                                  float* __restrict__ C, int M, int N, int K,
                                                  const float* __restrict__ P,
                                                  const float* __restrict__ l2sb,
                                                  const float* __restrict__ wl2s, float lscale){
  // row layout: 64 ushorts = 4 k-groups x [8 hi | 8 lo]; swizzle: off ^= (row&7)<<3 (ushort units)
  __shared__ unsigned short As[128 * 64];
  __shared__ unsigned short Bs[128 * 64];
  int tid = threadIdx.x;
  int n0 = blockIdx.x * 128, m0 = blockIdx.y * 128;
  int w = tid >> 6, lane = tid & 63;
  int wr = w >> 1, wc = w & 1;                   // 2x2 wave grid, 64x64 per wave
  int g = lane >> 4, q = lane & 15;              // MFMA fragment coords

  f32x4 acc[4][4];
  #pragma unroll
  for (int i = 0; i < 4; ++i)
    #pragma unroll
    for (int j = 0; j < 4; ++j) acc[i][j] = (f32x4){0.f, 0.f, 0.f, 0.f};

  for (int kk = 0; kk < K; kk += 32){
    // ---- stage A: 128 rows x 32 k fp32 -> hi/lo bf16 (2 k-groups per thread) ----
    #pragma unroll
    for (int s = 0; s < 2; ++s){
      int gi = tid + s * 256;                    // 0..511: row = gi>>2, kgroup = gi&3
      int m = gi >> 2, kb = gi & 3;
      const float* src = A + (size_t)(m0 + m) * K + kk + kb * 8;
      f32x4 x0 = *(const f32x4*)src;
      f32x4 x1 = *(const f32x4*)(src + 4);
      unsigned int h[8], l[8];
      #pragma unroll
      for (int j = 0; j < 8; ++j){
        float x = (j < 4) ? x0[j] : x1[j - 4];
        h[j] = f2bf(x);
        l[j] = f2bf(x - bf2f(h[j]));
      }
      u32x4 hv, lv;
      hv[0] = h[0] | (h[1] << 16); hv[1] = h[2] | (h[3] << 16);
      hv[2] = h[4] | (h[5] << 16); hv[3] = h[6] | (h[7] << 16);
      lv[0] = l[0] | (l[1] << 16); lv[1] = l[2] | (l[3] << 16);
      lv[2] = l[4] | (l[5] << 16); lv[3] = l[6] | (l[7] << 16);
      int sw = (m & 7) << 3;
      unsigned short* rp = &As[m * 64];
      *(u32x4*)&rp[(kb * 16) ^ sw]     = hv;
      *(u32x4*)&rp[(kb * 16 + 8) ^ sw] = lv;
    }
    // ---- stage B: pre-split global layout -> straight 16B copies ----
    #pragma unroll
    for (int s = 0; s < 4; ++s){
      int ci = tid + s * 256;                    // 0..1023: row = ci>>3, 16B-chunk = ci&7
      int n = ci >> 3, c = ci & 7;
      u32x4 v = *(const u32x4*)&WT[(size_t)(n0 + n) * 2 * K + kk * 2 + c * 8];
      int sw = (n & 7) << 3;
      *(u32x4*)&Bs[n * 64 + ((c * 8) ^ sw)] = v;
    }
    __syncthreads();

    // ---- fragments: lane holds 8 contiguous k (group g) of row/col q ----
    u32x4 aH[4], aL[4], bH[4], bL[4];
    #pragma unroll
    for (int f = 0; f < 4; ++f){
      int row = wr * 64 + f * 16 + q;
      int swa = (row & 7) << 3;
      const unsigned short* rp = &As[row * 64];
      aH[f] = *(const u32x4*)&rp[(g * 16) ^ swa];
      aL[f] = *(const u32x4*)&rp[(g * 16 + 8) ^ swa];
      int col = wc * 64 + f * 16 + q;
      int swb = (col & 7) << 3;
      const unsigned short* cp = &Bs[col * 64];
      bH[f] = *(const u32x4*)&cp[(g * 16) ^ swb];
      bL[f] = *(const u32x4*)&cp[(g * 16 + 8) ^ swb];
    }
    #pragma unroll
    for (int i = 0; i < 4; ++i)
      #pragma unroll
      for (int j = 0; j < 4; ++j){
        acc[i][j] = mfma_bf16(aH[i], bH[j], acc[i][j]);
        acc[i][j] = mfma_bf16(aH[i], bL[j], acc[i][j]);
        acc[i][j] = mfma_bf16(aL[i], bH[j], acc[i][j]);
      }
    __syncthreads();
  }

  // ---- epilogue: C/D layout col=lane&15, row=(lane>>4)*4+reg (m89-verified) ----
  float wv = 0.f;
  if (MODE == 3) wv = wl2s[0];
  #pragma unroll
  for (int i = 0; i < 4; ++i){
    #pragma unroll
    for (int r = 0; r < 4; ++r){
      int row = m0 + wr * 64 + i * 16 + g * 4 + r;
      int b = row / Tz, t = row % Tz;
      float ct = (t < LENS) ? (1.0f / LENS) : (1.0f / LENP);
      #pragma unroll
      for (int j = 0; j < 4; ++j){
        int col = n0 + wc * 64 + j * 16 + q;
        size_t idx = (size_t)row * N + col;
        float v = acc[i][j][r] + bias[col];
        if (MODE == 1) v += R[idx];
        if (MODE == 2) v = gelu_tanh(v);
        if (MODE == 3){
          v += R[idx];
          v += wv * ct * (lscale * P[b * Dz + col] + l2sb[col]);
        }
        C[idx] = v;
      }
    }
  }
}

// fused causal attention for one (b,h): scores+softmax (K in LDS, probs->global),
// then O = P@V (V in LDS).
__global__ __launch_bounds__(256) void k_attn(const float* __restrict__ qkv,
                                              float* __restrict__ probs,
                                              float* __restrict__ obuf){
  int bh = blockIdx.x; int b = bh / NHz, hh = bh % NHz;
  int tid = threadIdx.x, w = tid >> 6, lane = tid & 63;
  __shared__ float KV[HDz * (Tz + 1)];           // phase1: Kt[d][j] (stride 141); phase2: V[j][d]
  const float* base = qkv + (size_t)b * Tz * (3 * Dz);
  for (int idx = tid; idx < Tz * HDz; idx += 256){
    int j = idx >> 6, d = idx & 63;
    KV[d * (Tz + 1) + j] = base[(size_t)j * (3 * Dz) + Dz + hh * HDz + d];
  }
  __syncthreads();
  float* pb = probs + (size_t)bh * (Tz * Tz);
  for (int t = w; t < Tz; t += 4){
    const float* qr = base + (size_t)t * (3 * Dz) + hh * HDz;
    int j1 = lane + 64;
    int j2c = (lane + 128 < Tz) ? (lane + 128) : (Tz - 1);
    float a0 = 0.f, a1 = 0.f, a2 = 0.f;
    #pragma unroll 8
    for (int d = 0; d < HDz; ++d){
      float qv = qr[d];
      const float* kr = &KV[d * (Tz + 1)];
      a0 += qv * kr[lane];
      a1 += qv * kr[j1];
      a2 += qv * kr[j2c];
    }
    float s0 = (lane       <= t) ? a0 * 0.125f : -1e30f;
    float s1 = (lane + 64  <= t) ? a1 * 0.125f : -1e30f;
    float s2 = (lane + 128 <= t) ? a2 * 0.125f : -1e30f;
    float mx = wave_max(fmaxf(s0, fmaxf(s1, s2)));
    float e0 = (lane       <= t) ? expf(s0 - mx) : 0.f;
    float e1 = (lane + 64  <= t) ? expf(s1 - mx) : 0.f;
    float e2 = (lane + 128 <= t) ? expf(s2 - mx) : 0.f;
    float inv = 1.0f / wave_sum(e0 + e1 + e2);
    pb[t * Tz + lane] = e0 * inv;
    pb[t * Tz + lane + 64] = e1 * inv;
    if (lane + 128 < Tz) pb[t * Tz + lane + 128] = e2 * inv;
  }
  __threadfence_block();
  __syncthreads();
  for (int idx = tid; idx < Tz * HDz; idx += 256){
    int j = idx >> 6, d = idx & 63;
    KV[j * HDz + d] = base[(size_t)j * (3 * Dz) + 2 * Dz + hh * HDz + d];
  }
  __syncthreads();
  for (int t = w; t < Tz; t += 4){
    const float* pr = pb + t * Tz;
    float o = 0.f;
    #pragma unroll 4
    for (int j = 0; j < Tz; ++j) o += pr[j] * KV[j * HDz + lane];
    obuf[(size_t)(b * Tz + t) * Dz + hh * HDz + lane] = o;
  }
}

// chain-graph aggregation: h = h2 + ew_l*h2[t-1] + ew_r*h2[t+1]
__global__ void k_gnn(const float* __restrict__ h2, const float* __restrict__ ew,
                      float* __restrict__ h){
  size_t idx = (size_t)blockIdx.x * 256 + threadIdx.x;   // < NTOK*D
  int n = (int)(idx / Dz);
  int b = n / Tz, t = n % Tz;
  float v = h2[idx];
  if (t >= 1)      v += ew[b * EPBz + 2 * (t - 1)]     * h2[idx - Dz];
  if (t <= Tz - 2) v += ew[b * EPBz + 2 * t + 1]       * h2[idx + Dz];
  h[idx] = v;
}

// final LN + exact gelu
__global__ __launch_bounds__(256) void k_lnfgelu(const float* __restrict__ in, float* __restrict__ out,
                                                 const float* __restrict__ g, const float* __restrict__ bb){
  int row = blockIdx.x, tid = threadIdx.x;
  const float* r = in + (size_t)row * Dz;
  float v0 = r[tid], v1 = r[tid + 256], v2 = r[tid + 512];
  __shared__ float red[256];
  red[tid] = v0 + v1 + v2; __syncthreads();
  for (int s = 128; s; s >>= 1){ if (tid < s) red[tid] += red[tid + s]; __syncthreads(); }
  float mu = red[0] * (1.0f / Dz); __syncthreads();
  float d0 = v0 - mu, d1 = v1 - mu, d2 = v2 - mu;
  red[tid] = d0 * d0 + d1 * d1 + d2 * d2; __syncthreads();
  for (int s = 128; s; s >>= 1){ if (tid < s) red[tid] += red[tid + s]; __syncthreads(); }
  float rstd = rsqrtf(red[0] * (1.0f / Dz) + 1e-5f);
  float* o = out + (size_t)row * Dz;
  o[tid]       = gelu_exact(d0 * rstd * g[tid]       + bb[tid]);
  o[tid + 256] = gelu_exact(d1 * rstd * g[tid + 256] + bb[tid + 256]);
  o[tid + 512] = gelu_exact(d2 * rstd * g[tid + 512] + bb[tid + 512]);
}

// per-batch stats over ZDIM (fp64 accumulation)
__global__ __launch_bounds__(256) void k_zstats(const float* __restrict__ z, float* __restrict__ stat){
  int b = blockIdx.x, tid = threadIdx.x;
  const float* zr = z + (size_t)b * ZDIMz;
  double s = 0.0, qq = 0.0;
  for (int k = tid; k < ZDIMz; k += 256){ double v = zr[k]; s += v; qq += v * v; }
  __shared__ double rs_[256], rq_[256];
  rs_[tid] = s; rq_[tid] = qq; __syncthreads();
  for (int st = 128; st; st >>= 1){
    if (tid < st){ rs_[tid] += rs_[tid + st]; rq_[tid] += rq_[tid + st]; }
    __syncthreads();
  }
  if (tid == 0){
    double mu = rs_[0] / ZDIMz;
    double var = rq_[0] / ZDIMz - mu * mu;
    stat[b] = (float)mu;
    stat[64 + b] = (float)(1.0 / sqrt(var + 1e-5));
  }
}

// head: out[b,:] = LN(z_b)*g+b  @ out_w + out_b
__global__ __launch_bounds__(256) void k_head(const float* __restrict__ z, const float* __restrict__ stat,
                                              const float* __restrict__ lg, const float* __restrict__ lb,
                                              const float* __restrict__ W, const float* __restrict__ ob,
                                              float* __restrict__ out){
  int b = blockIdx.x, tid = threadIdx.x;
  float mu = stat[b], rs = stat[64 + b];
  const float* zr = z + (size_t)b * ZDIMz;
  float acc[NCLSz];
  #pragma unroll
  for (int j = 0; j < NCLSz; ++j) acc[j] = 0.f;
  for (int k = tid; k < ZDIMz; k += 256){
    float v = (zr[k] - mu) * rs * lg[k] + lb[k];
    const float* wr = W + (size_t)k * NCLSz;
    #pragma unroll
    for (int j = 0; j < NCLSz; ++j) acc[j] += v * wr[j];
  }
  __shared__ float red[256];
  for (int j = 0; j < NCLSz; ++j){
    red[tid] = acc[j]; __syncthreads();
    for (int s = 128; s; s >>= 1){ if (tid < s) red[tid] += red[tid + s]; __syncthreads(); }
    if (tid == 0) out[b * NCLSz + j] = red[0] + ob[j];
    __syncthreads();
  }
}

extern "C" void kernel_launch(void* const* d_in, const int* in_sizes, int n_in,
                              void* d_out, int out_size, void* d_ws, size_t ws_size,
                              hipStream_t stream){
  const float* x_enc  = (const float*)d_in[0];
  const float* conv_w = (const float*)d_in[2];
  const float* prompt = (const float*)d_in[3];
  const float* wpe    = (const float*)d_in[4];
  const float* ln1_g  = (const float*)d_in[5];
  const float* ln1_b  = (const float*)d_in[6];
  const float* attn_w = (const float*)d_in[7];
  const float* attn_b = (const float*)d_in[8];
  const float* proj_w = (const float*)d_in[9];
  const float* proj_b = (const float*)d_in[10];
  const float* ln2_g  = (const float*)d_in[11];
  const float* ln2_b  = (const float*)d_in[12];
  const float* fc1_w  = (const float*)d_in[13];
  const float* fc1_b  = (const float*)d_in[14];
  const float* fc2_w  = (const float*)d_in[15];
  const float* fc2_b  = (const float*)d_in[16];
  const float* lnf_g  = (const float*)d_in[17];
  const float* lnf_b  = (const float*)d_in[18];
  const float* ll1_w  = (const float*)d_in[19];
  const float* ll1_b  = (const float*)d_in[20];
  const float* ll0_w  = (const float*)d_in[21];
  const float* ll0_b  = (const float*)d_in[22];
  const float* l2s_w  = (const float*)d_in[23];
  const float* l2s_b  = (const float*)d_in[24];
  const float* w_l2s  = (const float*)d_in[25];
  const float* lnp_g  = (const float*)d_in[26];
  const float* lnp_b  = (const float*)d_in[27];
  const float* out_w  = (const float*)d_in[28];
  const float* out_b  = (const float*)d_in[29];
  const int*   eidx   = (const int*)d_in[30];
  const int*   eseg   = (const int*)d_in[31];
  float* out = (float*)d_out;

  float* ws = (float*)d_ws;
  const size_t SZ_H = (size_t)NTOKz * Dz;            // 6,881,280
  float* h0   = ws;
  float* hbuf = ws + SZ_H;
  float* xb   = ws + 2 * SZ_H;
  float* h2   = ws + 3 * SZ_H;
  float* qkv  = ws + 4 * SZ_H;                       // 20,643,840
  float* big  = qkv + (size_t)NTOKz * 3 * Dz;        // 27,525,120 (probs / mlp mid)
  float* pe   = big + (size_t)NTOKz * DMLPz;
  float* cwt  = pe + (size_t)LENS * Dz;
  float* sbuf = cwt + 144 * Dz;
  float* Pbuf = sbuf + Bz * Dz;
  float* nrm  = Pbuf + Bz * Dz;
  float* cosb = nrm + NTOKz;
  float* ewb  = cosb + Bz * EPBz;
  float* stat = ewb + Bz * EPBz;                     // 128 floats
  // rotating bf16-split weight buffer: max K*N = 768*3072 elems, hi+lo ushorts
  unsigned short* WT = (unsigned short*)(stat + 128);  // 4,718,592 ushorts = 9.44 MB

  // ---- phase A: encoder + graph weights + l2s precompute ----
  k_pe    <<<(LENS * Dz) / 256, 256, 0, stream>>>(pe);
  k_cwt   <<<(144 * Dz) / 256, 256, 0, stream>>>(conv_w, cwt);
  k_conv  <<<Bz * LENS, 256, 0, stream>>>(x_enc, cwt, pe, h0);
  k_prompt<<<(Bz * LENP * Dz) / 256, 256, 0, stream>>>(prompt, h0);
  k_norms <<<NTOKz, 64, 0, stream>>>(h0, nrm);
  k_ecos  <<<Bz * EPBz, 64, 0, stream>>>(h0, eidx, nrm, cosb);
  k_esoft <<<Bz, 256, 0, stream>>>(cosb, eseg, ewb);
  k_fills <<<(Bz * Dz) / 256, 256, 0, stream>>>(ll1_b, ll0_b, sbuf);
  k_splitk<<<dim3(Dz / 64, 96), 256, 0, stream>>>(h0, 0,     ll1_w, sbuf, KBIGz,  1024);
  k_splitk<<<dim3(Dz / 64, 9),  256, 0, stream>>>(h0, KBIGz, ll0_w, sbuf, KSMALLz, 1024);
  k_psmall<<<(Bz * Dz) / 256, 256, 0, stream>>>(sbuf, l2s_w, Pbuf);
  k_addwpe<<<(int)(SZ_H / 256), 256, 0, stream>>>(h0, wpe, hbuf);

  // ---- phase B: 6 transformer layers (GEMMs on MFMA via bf16x2 split) ----
  for (int l = 0; l < NLz; ++l){
    k_ln<<<NTOKz, 256, 0, stream>>>(hbuf, xb, ln1_g + l * Dz, ln1_b + l * Dz);

    k_wt<<<dim3(3 * Dz / 64, Dz / 64), 256, 0, stream>>>(
        attn_w + (size_t)l * Dz * 3 * Dz, WT, Dz, 3 * Dz);
    k_bgemm<0><<<dim3(3 * Dz / 128, NTOKz / 128), 256, 0, stream>>>(
        xb, WT, attn_b + l * 3 * Dz, nullptr, qkv,
        NTOKz, 3 * Dz, Dz, nullptr, nullptr, nullptr, 0.f);

    k_attn<<<Bz * NHz, 256, 0, stream>>>(qkv, big, xb);

    k_wt<<<dim3(Dz / 64, Dz / 64), 256, 0, stream>>>(
        proj_w + (size_t)l * Dz * Dz, WT, Dz, Dz);
    k_bgemm<1><<<dim3(Dz / 128, NTOKz / 128), 256, 0, stream>>>(
        xb, WT, proj_b + l * Dz, hbuf, h2,
        NTOKz, Dz, Dz, nullptr, nullptr, nullptr, 0.f);

    k_gnn<<<(int)(SZ_H / 256), 256, 0, stream>>>(h2, ewb, hbuf);
    k_ln<<<NTOKz, 256, 0, stream>>>(hbuf, xb, ln2_g + l * Dz, ln2_b + l * Dz);

    k_wt<<<dim3(DMLPz / 64, Dz / 64), 256, 0, stream>>>(
        fc1_w + (size_t)l * Dz * DMLPz, WT, Dz, DMLPz);
    k_bgemm<2><<<dim3(DMLPz / 128, NTOKz / 128), 256, 0, stream>>>(
        xb, WT, fc1_b + l * DMLPz, nullptr, big,
        NTOKz, DMLPz, Dz, nullptr, nullptr, nullptr, 0.f);

    k_wt<<<dim3(Dz / 64, DMLPz / 64), 256, 0, stream>>>(
        fc2_w + (size_t)l * DMLPz * Dz, WT, DMLPz, Dz);
    k_bgemm<3><<<dim3(Dz / 128, NTOKz / 128), 256, 0, stream>>>(
        big, WT, fc2_b + l * Dz, hbuf, hbuf,
        NTOKz, Dz, DMLPz, Pbuf, l2s_b, w_l2s, (float)(1 << l));
  }

  // ---- phase C: final LN + gelu + big LN + head ----
  k_lnfgelu<<<NTOKz, 256, 0, stream>>>(hbuf, xb, lnf_g, lnf_b);
  k_zstats <<<Bz, 256, 0, stream>>>(xb, stat);
  k_head   <<<Bz, 256, 0, stream>>>(xb, stat, lnp_g, lnp_b, out_w, out_b, out);
}

// Round 4
// 4855.691 us; speedup vs baseline: 1.3812x; 1.3812x over previous
//
#include <hip/hip_runtime.h>
#include <math.h>

// ---------------- problem constants ----------------
#define Bz     64
#define LENS   128
#define LENP   12
#define Tz     140
#define Dz     768
#define NHz    12
#define HDz    64
#define NLz    6
#define DMLPz  3072
#define NCLSz  10
#define EPBz   278                 // edges per batch = 2*(T-1)
#define NTOKz  (Bz*Tz)             // 8960
#define ZDIMz  (Tz*Dz)             // 107520
#define KBIGz  (LENS*Dz)           // 98304
#define KSMALLz (LENP*Dz)          // 9216
#define PSTR   168                 // P/V panel stride in ushorts (336B, 16B-aligned rows)

typedef float f32x4 __attribute__((ext_vector_type(4)));
typedef unsigned int u32x4 __attribute__((ext_vector_type(4)));
typedef short short8 __attribute__((ext_vector_type(8)));

__device__ __forceinline__ float wave_sum(float v){
  #pragma unroll
  for (int m = 32; m; m >>= 1) v += __shfl_xor(v, m);
  return v;
}
__device__ __forceinline__ float wave_max(float v){
  #pragma unroll
  for (int m = 32; m; m >>= 1) v = fmaxf(v, __shfl_xor(v, m));
  return v;
}
// reduce across the 16-lane group that shares one MFMA C/D row set
__device__ __forceinline__ float red16_max(float v){
  v = fmaxf(v, __shfl_xor(v, 1));
  v = fmaxf(v, __shfl_xor(v, 2));
  v = fmaxf(v, __shfl_xor(v, 4));
  v = fmaxf(v, __shfl_xor(v, 8));
  return v;
}
__device__ __forceinline__ float red16_sum(float v){
  v += __shfl_xor(v, 1); v += __shfl_xor(v, 2);
  v += __shfl_xor(v, 4); v += __shfl_xor(v, 8);
  return v;
}
__device__ __forceinline__ float gelu_tanh(float u){
  float c = 0.7978845608028654f * (u + 0.044715f * u * u * u);
  return 0.5f * u * (1.0f + tanhf(c));
}
__device__ __forceinline__ float gelu_exact(float u){
  return 0.5f * u * (1.0f + erff(u * 0.7071067811865476f));
}

// float -> bf16 (RNE) and back
__device__ __forceinline__ unsigned int f2bf(float x){
  unsigned int u = __float_as_uint(x);
  return (u + 0x7fffu + ((u >> 16) & 1u)) >> 16;
}
__device__ __forceinline__ float bf2f(unsigned int h){
  return __uint_as_float(h << 16);
}

// v_mfma_f32_16x16x32_bf16 via inline asm (verified in k_bgemm round 1 — keep)
__device__ __forceinline__ f32x4 mfma_bf16(u32x4 a, u32x4 b, f32x4 c){
  asm("v_mfma_f32_16x16x32_bf16 %0, %1, %2, %0" : "+v"(c) : "v"(a), "v"(b));
  return c;
}

// builtin MFMA (compiler-visible: hazard nops + scheduling handled) for k_attn2
__device__ __forceinline__ short8 pun(u32x4 u){
  union { u32x4 u; short8 s; } x; x.u = u; return x.s;
}
__device__ __forceinline__ f32x4 mfma_b(u32x4 a, u32x4 b, f32x4 c){
  return __builtin_amdgcn_mfma_f32_16x16x32_bf16(pun(a), pun(b), c, 0, 0, 0);
}

// 8 consecutive fp32 -> bf16 hi/lo packed operands
__device__ __forceinline__ void cvt_hilo(f32x4 x0, f32x4 x1, u32x4& h, u32x4& l){
  unsigned int h0 = f2bf(x0[0]), h1 = f2bf(x0[1]), h2 = f2bf(x0[2]), h3 = f2bf(x0[3]);
  unsigned int h4 = f2bf(x1[0]), h5 = f2bf(x1[1]), h6 = f2bf(x1[2]), h7 = f2bf(x1[3]);
  unsigned int l0 = f2bf(x0[0] - bf2f(h0)), l1 = f2bf(x0[1] - bf2f(h1));
  unsigned int l2 = f2bf(x0[2] - bf2f(h2)), l3 = f2bf(x0[3] - bf2f(h3));
  unsigned int l4 = f2bf(x1[0] - bf2f(h4)), l5 = f2bf(x1[1] - bf2f(h5));
  unsigned int l6 = f2bf(x1[2] - bf2f(h6)), l7 = f2bf(x1[3] - bf2f(h7));
  h[0] = h0 | (h1 << 16); h[1] = h2 | (h3 << 16);
  h[2] = h4 | (h5 << 16); h[3] = h6 | (h7 << 16);
  l[0] = l0 | (l1 << 16); l[1] = l2 | (l3 << 16);
  l[2] = l4 | (l5 << 16); l[3] = l6 | (l7 << 16);
}

// ---------------- positional encoding (once) ----------------
__global__ void k_pe(float* pe){
  int idx = blockIdx.x * 256 + threadIdx.x;      // < 128*768
  int s = idx / Dz, o = idx % Dz;
  int ie = o & ~1;
  double ang = (double)s * pow(10000.0, -(double)ie / (double)Dz);
  pe[idx] = (o & 1) ? (float)cos(ang) : (float)sin(ang);
}

// transpose conv_w (768,48,3) -> cwt[(k*48+i)*768 + o]
__global__ void k_cwt(const float* __restrict__ cw, float* __restrict__ cwt){
  int idx = blockIdx.x * 256 + threadIdx.x;      // < 144*768
  int o = idx % Dz, j = idx / Dz;                // j = k*48+i
  int i = j % 48, k = j / 48;
  cwt[j * Dz + o] = cw[o * 144 + i * 3 + k];
}

// conv encoder: one block per (b,s); h0[b,s,:] = conv + PE
__global__ __launch_bounds__(256) void k_conv(const float* __restrict__ x_enc,
                                              const float* __restrict__ cwt,
                                              const float* __restrict__ pe,
                                              float* __restrict__ h0){
  int b = blockIdx.x / LENS, s = blockIdx.x % LENS;
  int tid = threadIdx.x;
  __shared__ float in144[144];
  if (tid < 144){
    int k = tid / 48, i = tid % 48;
    int sp = (s + k - 1 + LENS) % LENS;          // circular-padded inp column
    int p = i / 3, m = i % 3;
    int j = sp * 8 + p; if (j > 1023) j = 1023;  // repeat last timestep
    in144[tid] = x_enc[(b * 1024 + j) * 3 + m];
  }
  __syncthreads();
  for (int o = tid; o < Dz; o += 256){
    float acc = pe[s * Dz + o];
    #pragma unroll 8
    for (int j = 0; j < 144; ++j) acc += in144[j] * cwt[j * Dz + o];
    h0[((size_t)(b * Tz + s)) * Dz + o] = acc;
  }
}

__global__ void k_prompt(const float* __restrict__ pr, float* __restrict__ h0){
  int idx = blockIdx.x * 256 + threadIdx.x;      // < 64*12*768
  int b = idx / (LENP * Dz), r = idx % (LENP * Dz);
  h0[((size_t)(b * Tz + LENS)) * Dz + r] = pr[r];
}

// node L2 norms (one wave per node)
__global__ void k_norms(const float* __restrict__ h0, float* __restrict__ nrm){
  int n = blockIdx.x, lane = threadIdx.x;
  const float* r = h0 + (size_t)n * Dz;
  float s = 0.f;
  for (int d = lane; d < Dz; d += 64){ float v = r[d]; s += v * v; }
  s = wave_sum(s);
  if (lane == 0) nrm[n] = sqrtf(s);
}

// per-edge cosine (one wave per edge)
__global__ void k_ecos(const float* __restrict__ h0, const int* __restrict__ eidx,
                       const float* __restrict__ nrm, float* __restrict__ cosb){
  int e = blockIdx.x, lane = threadIdx.x;
  int sN = eidx[e], dN = eidx[Bz * EPBz + e];
  const float* a = h0 + (size_t)sN * Dz;
  const float* b = h0 + (size_t)dN * Dz;
  float s = 0.f;
  for (int d = lane; d < Dz; d += 64) s += a[d] * b[d];
  s = wave_sum(s);
  if (lane == 0) cosb[e] = s / (nrm[sN] * nrm[dN] + 1e-8f);
}

// segment softmax (2 segments per batch), one block per batch
__global__ __launch_bounds__(256) void k_esoft(const float* __restrict__ cosb,
                                               const int* __restrict__ eseg,
                                               float* __restrict__ ew){
  int b = blockIdx.x, tid = threadIdx.x;
  __shared__ float c[EPBz];
  __shared__ unsigned char gg[EPBz];
  __shared__ float r0[256], r1[256];
  for (int e = tid; e < EPBz; e += 256){
    c[e] = cosb[b * EPBz + e];
    gg[e] = (unsigned char)(eseg[b * EPBz + e] - 2 * b);
  }
  __syncthreads();
  float m0 = -1e30f, m1 = -1e30f;
  for (int e = tid; e < EPBz; e += 256){
    if (gg[e]) m1 = fmaxf(m1, c[e]); else m0 = fmaxf(m0, c[e]);
  }
  r0[tid] = m0; r1[tid] = m1; __syncthreads();
  for (int s = 128; s; s >>= 1){
    if (tid < s){ r0[tid] = fmaxf(r0[tid], r0[tid+s]); r1[tid] = fmaxf(r1[tid], r1[tid+s]); }
    __syncthreads();
  }
  m0 = r0[0]; m1 = r1[0]; __syncthreads();
  float s0 = 0.f, s1 = 0.f;
  for (int e = tid; e < EPBz; e += 256){
    float ex = expf(c[e] - (gg[e] ? m1 : m0));
    c[e] = ex;
    if (gg[e]) s1 += ex; else s0 += ex;
  }
  r0[tid] = s0; r1[tid] = s1; __syncthreads();
  for (int s = 128; s; s >>= 1){
    if (tid < s){ r0[tid] += r0[tid+s]; r1[tid] += r1[tid+s]; }
    __syncthreads();
  }
  s0 = r0[0]; s1 = r1[0];
  for (int e = tid; e < EPBz; e += 256)
    ew[b * EPBz + e] = c[e] / ((gg[e] ? s1 : s0) + 1e-8f);
}

// s init with both biases
__global__ void k_fills(const float* __restrict__ b1, const float* __restrict__ b0,
                        float* __restrict__ sbuf){
  int idx = blockIdx.x * 256 + threadIdx.x;      // < 64*768
  int d = idx % Dz;
  sbuf[idx] = b1[d] + b0[d];
}

// split-K GEMM: C(64x768) += A(64 x K) @ W(K x 768); A rows stride ZDIM in h0
__global__ __launch_bounds__(256) void k_splitk(const float* __restrict__ Abase, int aOff,
                                                const float* __restrict__ W,
                                                float* __restrict__ Cacc,
                                                int K, int kChunk){
  __shared__ __align__(16) float As[16 * 65];
  __shared__ __align__(16) float Ws[16 * 64];
  int tid = threadIdx.x, tx = tid % 16, ty = tid / 16;
  int n0 = blockIdx.x * 64;
  int kb = blockIdx.y * kChunk;
  int ke = kb + kChunk; if (ke > K) ke = K;
  float acc[16];
  #pragma unroll
  for (int i = 0; i < 16; ++i) acc[i] = 0.f;
  for (int kk = kb; kk < ke; kk += 16){
    #pragma unroll
    for (int r = 0; r < 4; ++r){
      int idx = tid + r * 256; int k = idx & 15, m = idx >> 4;   // m in [0,64)
      As[k * 65 + m] = Abase[(size_t)m * ZDIMz + aOff + kk + k];
    }
    #pragma unroll
    for (int r = 0; r < 4; ++r){
      int idx = tid + r * 256; int n = idx & 63, k = idx >> 6;
      Ws[k * 64 + n] = W[(size_t)(kk + k) * Dz + n0 + n];
    }
    __syncthreads();
    #pragma unroll
    for (int k = 0; k < 16; ++k){
      float a[4], bvv[4];
      #pragma unroll
      for (int i = 0; i < 4; ++i) a[i] = As[k * 65 + ty * 4 + i];
      #pragma unroll
      for (int j = 0; j < 4; ++j) bvv[j] = Ws[k * 64 + tx * 4 + j];
      #pragma unroll
      for (int i = 0; i < 4; ++i)
        #pragma unroll
        for (int j = 0; j < 4; ++j) acc[i * 4 + j] += a[i] * bvv[j];
    }
    __syncthreads();
  }
  #pragma unroll
  for (int i = 0; i < 4; ++i)
    #pragma unroll
    for (int j = 0; j < 4; ++j)
      atomicAdd(&Cacc[(size_t)(ty * 4 + i) * Dz + n0 + tx * 4 + j], acc[i * 4 + j]);
}

// P[b,d] = sum_{c<128} s[b,c]*l2s_w[c,d]
__global__ void k_psmall(const float* __restrict__ sbuf, const float* __restrict__ l2sw,
                         float* __restrict__ P){
  int idx = blockIdx.x * 256 + threadIdx.x;      // < 64*768
  int b = idx / Dz, d = idx % Dz;
  float acc = 0.f;
  #pragma unroll 8
  for (int c = 0; c < 128; ++c) acc += sbuf[b * Dz + c] * l2sw[c * Dz + d];
  P[idx] = acc;
}

__global__ void k_addwpe(const float* __restrict__ h0, const float* __restrict__ wpe,
                         float* __restrict__ h){
  size_t idx = (size_t)blockIdx.x * 256 + threadIdx.x;   // < NTOK*D
  int n = (int)(idx / Dz), d = (int)(idx % Dz);
  int t = n % Tz;
  h[idx] = h0[idx] + wpe[t * Dz + d];
}

// row layernorm over D=768, block per row (3 elems per thread)
__global__ __launch_bounds__(256) void k_ln(const float* __restrict__ in, float* __restrict__ out,
                                            const float* __restrict__ g, const float* __restrict__ bb){
  int row = blockIdx.x, tid = threadIdx.x;
  const float* r = in + (size_t)row * Dz;
  float v0 = r[tid], v1 = r[tid + 256], v2 = r[tid + 512];
  __shared__ float red[256];
  red[tid] = v0 + v1 + v2; __syncthreads();
  for (int s = 128; s; s >>= 1){ if (tid < s) red[tid] += red[tid + s]; __syncthreads(); }
  float mu = red[0] * (1.0f / Dz); __syncthreads();
  float d0 = v0 - mu, d1 = v1 - mu, d2 = v2 - mu;
  red[tid] = d0 * d0 + d1 * d1 + d2 * d2; __syncthreads();
  for (int s = 128; s; s >>= 1){ if (tid < s) red[tid] += red[tid + s]; __syncthreads(); }
  float rstd = rsqrtf(red[0] * (1.0f / Dz) + 1e-5f);
  float* o = out + (size_t)row * Dz;
  o[tid]       = d0 * rstd * g[tid]       + bb[tid];
  o[tid + 256] = d1 * rstd * g[tid + 256] + bb[tid + 256];
  o[tid + 512] = d2 * rstd * g[tid + 512] + bb[tid + 512];
}

// ---------------------------------------------------------------------------
// weight transpose+split kernel: W[K][N] fp32 -> WT[N][K/8 groups][8 hi|8 lo] bf16
// ---------------------------------------------------------------------------
__global__ __launch_bounds__(256) void k_wt(const float* __restrict__ W,
                                            unsigned short* __restrict__ WT,
                                            int K, int N){
  __shared__ float T[64][65];
  int k0 = blockIdx.y * 64, n0v = blockIdx.x * 64;
  int tid = threadIdx.x;
  int tx = tid & 15, ty = tid >> 4;
  #pragma unroll
  for (int rr = 0; rr < 4; ++rr){
    int row = rr * 16 + ty;
    const float* src = &W[(size_t)(k0 + row) * N + n0v + tx * 4];
    f32x4 v = *(const f32x4*)src;
    T[row][tx * 4]     = v[0];
    T[row][tx * 4 + 1] = v[1];
    T[row][tx * 4 + 2] = v[2];
    T[row][tx * 4 + 3] = v[3];
  }
  __syncthreads();
  #pragma unroll
  for (int s = 0; s < 2; ++s){
    int gi = tid + s * 256;                      // 0..511  (64 n  x 8 k-groups)
    int n = gi >> 3, kg = gi & 7;
    unsigned int h[8], l[8];
    #pragma unroll
    for (int j = 0; j < 8; ++j){
      float x = T[kg * 8 + j][n];
      h[j] = f2bf(x);
      l[j] = f2bf(x - bf2f(h[j]));
    }
    u32x4 hv, lv;
    hv[0] = h[0] | (h[1] << 16); hv[1] = h[2] | (h[3] << 16);
    hv[2] = h[4] | (h[5] << 16); hv[3] = h[6] | (h[7] << 16);
    lv[0] = l[0] | (l[1] << 16); lv[1] = l[2] | (l[3] << 16);
    lv[2] = l[4] | (l[5] << 16); lv[3] = l[6] | (l[7] << 16);
    size_t base = (size_t)(n0v + n) * 2 * K + (size_t)(k0 / 8 + kg) * 16;
    *(u32x4*)&WT[base]     = hv;
    *(u32x4*)&WT[base + 8] = lv;
  }
}

// ---------------------------------------------------------------------------
// bf16x2-split MFMA GEMM (verified round 1 — unchanged)
// ---------------------------------------------------------------------------
template<int MODE>
__global__ __launch_bounds__(256, 2) void k_bgemm(const float* __restrict__ A,
                                                  const unsigned short* __restrict__ WT,
                                                  const float* __restrict__ bias,
                                                  const float* __restrict__ R,
                                                  float* __restrict__ C, int M, int N, int K,
                                                  const float* __restrict__ P,
                                                  const float* __restrict__ l2sb,
                                                  const float* __restrict__ wl2s, float lscale){
  __shared__ __align__(16) unsigned short As[128 * 64];
  __shared__ __align__(16) unsigned short Bs[128 * 64];
  int tid = threadIdx.x;
  int n0 = blockIdx.x * 128, m0 = blockIdx.y * 128;
  int w = tid >> 6, lane = tid & 63;
  int wr = w >> 1, wc = w & 1;
  int g = lane >> 4, q = lane & 15;

  f32x4 acc[4][4];
  #pragma unroll
  for (int i = 0; i < 4; ++i)
    #pragma unroll
    for (int j = 0; j < 4; ++j) acc[i][j] = (f32x4){0.f, 0.f, 0.f, 0.f};

  for (int kk = 0; kk < K; kk += 32){
    #pragma unroll
    for (int s = 0; s < 2; ++s){
      int gi = tid + s * 256;
      int m = gi >> 2, kb = gi & 3;
      const float* src = A + (size_t)(m0 + m) * K + kk + kb * 8;
      f32x4 x0 = *(const f32x4*)src;
      f32x4 x1 = *(const f32x4*)(src + 4);
      u32x4 hv, lv;
      cvt_hilo(x0, x1, hv, lv);
      int sw = (m & 7) << 3;
      unsigned short* rp = &As[m * 64];
      *(u32x4*)&rp[(kb * 16) ^ sw]     = hv;
      *(u32x4*)&rp[(kb * 16 + 8) ^ sw] = lv;
    }
    #pragma unroll
    for (int s = 0; s < 4; ++s){
      int ci = tid + s * 256;
      int n = ci >> 3, c = ci & 7;
      u32x4 v = *(const u32x4*)&WT[(size_t)(n0 + n) * 2 * K + kk * 2 + c * 8];
      int sw = (n & 7) << 3;
      *(u32x4*)&Bs[n * 64 + ((c * 8) ^ sw)] = v;
    }
    __syncthreads();

    u32x4 aH[4], aL[4], bH[4], bL[4];
    #pragma unroll
    for (int f = 0; f < 4; ++f){
      int row = wr * 64 + f * 16 + q;
      int swa = (row & 7) << 3;
      const unsigned short* rp = &As[row * 64];
      aH[f] = *(const u32x4*)&rp[(g * 16) ^ swa];
      aL[f] = *(const u32x4*)&rp[(g * 16 + 8) ^ swa];
      int col = wc * 64 + f * 16 + q;
      int swb = (col & 7) << 3;
      const unsigned short* cp = &Bs[col * 64];
      bH[f] = *(const u32x4*)&cp[(g * 16) ^ swb];
      bL[f] = *(const u32x4*)&cp[(g * 16 + 8) ^ swb];
    }
    #pragma unroll
    for (int i = 0; i < 4; ++i)
      #pragma unroll
      for (int j = 0; j < 4; ++j){
        acc[i][j] = mfma_bf16(aH[i], bH[j], acc[i][j]);
        acc[i][j] = mfma_bf16(aH[i], bL[j], acc[i][j]);
        acc[i][j] = mfma_bf16(aL[i], bH[j], acc[i][j]);
      }
    __syncthreads();
  }

  float wv = 0.f;
  if (MODE == 3) wv = wl2s[0];
  #pragma unroll
  for (int i = 0; i < 4; ++i){
    #pragma unroll
    for (int r = 0; r < 4; ++r){
      int row = m0 + wr * 64 + i * 16 + g * 4 + r;
      int b = row / Tz, t = row % Tz;
      float ct = (t < LENS) ? (1.0f / LENS) : (1.0f / LENP);
      #pragma unroll
      for (int j = 0; j < 4; ++j){
        int col = n0 + wc * 64 + j * 16 + q;
        size_t idx = (size_t)row * N + col;
        float v = acc[i][j][r] + bias[col];
        if (MODE == 1) v += R[idx];
        if (MODE == 2) v = gelu_tanh(v);
        if (MODE == 3){
          v += R[idx];
          v += wv * ct * (lscale * P[b * Dz + col] + l2sb[col]);
        }
        C[idx] = v;
      }
    }
  }
}

// ---------------------------------------------------------------------------
// MFMA flash attention v3: one block per (b,h), 8 waves, wave w owns 16-row
// S-tiles {w, w+8}. BUILTIN mfma (hazard-safe). Q,K bf16 hi/lo from global;
// S in registers; softmax via 16-lane shuffles; P (single bf16) through a
// per-wave LDS panel written ONCE per tile, fully initialized (cols 0..159);
// V staged once as bf16 [d][j], rows >=140 zeroed. PV = 1 MFMA per step.
// ---------------------------------------------------------------------------
__global__ __launch_bounds__(512, 1) void k_attn2(const float* __restrict__ qkv,
                                                  float* __restrict__ obuf){
  int bh = blockIdx.x; int b = bh / NHz, hh = bh % NHz;
  int tid = threadIdx.x, w = tid >> 6, lane = tid & 63;
  int g = lane >> 4, q = lane & 15;

  __shared__ __align__(16) unsigned short Vb[64 * PSTR];      // 21504 B
  __shared__ __align__(16) unsigned short Pp[8][16 * PSTR];   // 43008 B

  const float* base = qkv + (size_t)b * Tz * (3 * Dz) + hh * HDz;

  // ---- stage Vb[d][j] = bf16(V[j][d]); zero cols j in [140,160) ----
  for (int e = tid; e < 64 * 160; e += 512){
    int d = e / 160, j = e - d * 160;
    float v = (j < Tz) ? base[(size_t)j * (3 * Dz) + 2 * Dz + d] : 0.f;
    Vb[d * PSTR + j] = (unsigned short)f2bf(v);
  }
  __syncthreads();

  unsigned short* Pw = &Pp[w][0];

  for (int tile = w; tile < 9; tile += 8){
    int i0 = tile * 16;

    // ---- Q A-frags (row = i0+q, k-tiles 0,1) direct from global ----
    u32x4 qh[2], ql[2];
    {
      int row = i0 + q; if (row > Tz - 1) row = Tz - 1;
      const float* qp = base + (size_t)row * (3 * Dz);
      #pragma unroll
      for (int kt = 0; kt < 2; ++kt){
        f32x4 x0 = *(const f32x4*)(qp + kt * 32 + g * 8);
        f32x4 x1 = *(const f32x4*)(qp + kt * 32 + g * 8 + 4);
        cvt_hilo(x0, x1, qh[kt], ql[kt]);
      }
    }

    // ---- S = Q K^T over col-tiles 0..tile (causal skip), bf16x2 ----
    f32x4 acc[9];
    #pragma unroll
    for (int j = 0; j < 9; ++j) acc[j] = (f32x4){0.f, 0.f, 0.f, 0.f};
    #pragma unroll
    for (int j = 0; j < 9; ++j){
      if (j > tile) continue;
      int col = j * 16 + q; if (col > Tz - 1) col = Tz - 1;
      const float* kp = base + (size_t)col * (3 * Dz) + Dz;
      #pragma unroll
      for (int kt = 0; kt < 2; ++kt){
        f32x4 x0 = *(const f32x4*)(kp + kt * 32 + g * 8);
        f32x4 x1 = *(const f32x4*)(kp + kt * 32 + g * 8 + 4);
        u32x4 kh, kl;
        cvt_hilo(x0, x1, kh, kl);
        acc[j] = mfma_b(qh[kt], kh, acc[j]);
        acc[j] = mfma_b(qh[kt], kl, acc[j]);
        acc[j] = mfma_b(ql[kt], kh, acc[j]);
      }
    }

    // ---- row softmax (C/D layout: col=q, row=g*4+r) ----
    #pragma unroll
    for (int r = 0; r < 4; ++r){
      int t = i0 + g * 4 + r;                    // global query row
      float mx = -1e30f;
      #pragma unroll
      for (int j = 0; j < 9; ++j){
        if (j > tile) continue;
        int col = j * 16 + q;
        float s = acc[j][r] * 0.125f;
        bool valid = (col <= t) && (col < Tz);
        s = valid ? s : -1e30f;
        acc[j][r] = s;
        mx = fmaxf(mx, s);
      }
      mx = red16_max(mx);
      float sum = 0.f;
      #pragma unroll
      for (int j = 0; j < 9; ++j){
        if (j > tile) continue;
        float e = expf(acc[j][r] - mx);
        acc[j][r] = e;
        sum += e;
      }
      sum = red16_sum(sum);
      float inv = 1.0f / sum;
      #pragma unroll
      for (int j = 0; j < 9; ++j){
        if (j > tile) continue;
        acc[j][r] *= inv;
      }
    }

    // ---- write FULL P panel (bf16): rows 0..15 x cols 0..159, zeros beyond ----
    #pragma unroll
    for (int j = 0; j < 10; ++j){
      const int jc = (j < 9) ? j : 0;            // static in-bounds index
      #pragma unroll
      for (int r = 0; r < 4; ++r){
        float p = (j < 9 && j <= tile) ? acc[jc][r] : 0.f;
        Pw[(g * 4 + r) * PSTR + j * 16 + q] = (unsigned short)f2bf(p);
      }
    }
    // fence: in-wave cross-lane LDS write->read ordering (rule #18 pattern)
    __builtin_amdgcn_sched_barrier(0);
    asm volatile("s_waitcnt lgkmcnt(0)" ::: "memory");
    __builtin_amdgcn_sched_barrier(0);

    // ---- O = P V (single-bf16 operands, 1 MFMA per step) ----
    f32x4 oacc[4];
    #pragma unroll
    for (int dt = 0; dt < 4; ++dt) oacc[dt] = (f32x4){0.f, 0.f, 0.f, 0.f};
    #pragma unroll
    for (int kt = 0; kt < 5; ++kt){
      if (kt > (tile >> 1)) continue;
      u32x4 pa = *(const u32x4*)&Pw[q * PSTR + kt * 32 + g * 8];
      #pragma unroll
      for (int dt = 0; dt < 4; ++dt){
        u32x4 vv = *(const u32x4*)&Vb[(dt * 16 + q) * PSTR + kt * 32 + g * 8];
        oacc[dt] = mfma_b(pa, vv, oacc[dt]);
      }
    }

    // ---- store O rows < T ----
    #pragma unroll
    for (int r = 0; r < 4; ++r){
      int t = i0 + g * 4 + r;
      if (t < Tz){
        float* op = obuf + (size_t)(b * Tz + t) * Dz + hh * HDz;
        #pragma unroll
        for (int dt = 0; dt < 4; ++dt) op[dt * 16 + q] = oacc[dt][r];
      }
    }
  }
}

// chain-graph aggregation: h = h2 + ew_l*h2[t-1] + ew_r*h2[t+1]
__global__ void k_gnn(const float* __restrict__ h2, const float* __restrict__ ew,
                      float* __restrict__ h){
  size_t idx = (size_t)blockIdx.x * 256 + threadIdx.x;   // < NTOK*D
  int n = (int)(idx / Dz);
  int b = n / Tz, t = n % Tz;
  float v = h2[idx];
  if (t >= 1)      v += ew[b * EPBz + 2 * (t - 1)]     * h2[idx - Dz];
  if (t <= Tz - 2) v += ew[b * EPBz + 2 * t + 1]       * h2[idx + Dz];
  h[idx] = v;
}

// final LN + exact gelu
__global__ __launch_bounds__(256) void k_lnfgelu(const float* __restrict__ in, float* __restrict__ out,
                                                 const float* __restrict__ g, const float* __restrict__ bb){
  int row = blockIdx.x, tid = threadIdx.x;
  const float* r = in + (size_t)row * Dz;
  float v0 = r[tid], v1 = r[tid + 256], v2 = r[tid + 512];
  __shared__ float red[256];
  red[tid] = v0 + v1 + v2; __syncthreads();
  for (int s = 128; s; s >>= 1){ if (tid < s) red[tid] += red[tid + s]; __syncthreads(); }
  float mu = red[0] * (1.0f / Dz); __syncthreads();
  float d0 = v0 - mu, d1 = v1 - mu, d2 = v2 - mu;
  red[tid] = d0 * d0 + d1 * d1 + d2 * d2; __syncthreads();
  for (int s = 128; s; s >>= 1){ if (tid < s) red[tid] += red[tid + s]; __syncthreads(); }
  float rstd = rsqrtf(red[0] * (1.0f / Dz) + 1e-5f);
  float* o = out + (size_t)row * Dz;
  o[tid]       = gelu_exact(d0 * rstd * g[tid]       + bb[tid]);
  o[tid + 256] = gelu_exact(d1 * rstd * g[tid + 256] + bb[tid + 256]);
  o[tid + 512] = gelu_exact(d2 * rstd * g[tid + 512] + bb[tid + 512]);
}

// per-batch stats over ZDIM (fp64 accumulation)
__global__ __launch_bounds__(256) void k_zstats(const float* __restrict__ z, float* __restrict__ stat){
  int b = blockIdx.x, tid = threadIdx.x;
  const float* zr = z + (size_t)b * ZDIMz;
  double s = 0.0, qq = 0.0;
  for (int k = tid; k < ZDIMz; k += 256){ double v = zr[k]; s += v; qq += v * v; }
  __shared__ double rs_[256], rq_[256];
  rs_[tid] = s; rq_[tid] = qq; __syncthreads();
  for (int st = 128; st; st >>= 1){
    if (tid < st){ rs_[tid] += rs_[tid + st]; rq_[tid] += rq_[tid + st]; }
    __syncthreads();
  }
  if (tid == 0){
    double mu = rs_[0] / ZDIMz;
    double var = rq_[0] / ZDIMz - mu * mu;
    stat[b] = (float)mu;
    stat[64 + b] = (float)(1.0 / sqrt(var + 1e-5));
  }
}

// head: out[b,:] = LN(z_b)*g+b  @ out_w + out_b
__global__ __launch_bounds__(256) void k_head(const float* __restrict__ z, const float* __restrict__ stat,
                                              const float* __restrict__ lg, const float* __restrict__ lb,
                                              const float* __restrict__ W, const float* __restrict__ ob,
                                              float* __restrict__ out){
  int b = blockIdx.x, tid = threadIdx.x;
  float mu = stat[b], rs = stat[64 + b];
  const float* zr = z + (size_t)b * ZDIMz;
  float acc[NCLSz];
  #pragma unroll
  for (int j = 0; j < NCLSz; ++j) acc[j] = 0.f;
  for (int k = tid; k < ZDIMz; k += 256){
    float v = (zr[k] - mu) * rs * lg[k] + lb[k];
    const float* wr = W + (size_t)k * NCLSz;
    #pragma unroll
    for (int j = 0; j < NCLSz; ++j) acc[j] += v * wr[j];
  }
  __shared__ float red[256];
  for (int j = 0; j < NCLSz; ++j){
    red[tid] = acc[j]; __syncthreads();
    for (int s = 128; s; s >>= 1){ if (tid < s) red[tid] += red[tid + s]; __syncthreads(); }
    if (tid == 0) out[b * NCLSz + j] = red[0] + ob[j];
    __syncthreads();
  }
}

extern "C" void kernel_launch(void* const* d_in, const int* in_sizes, int n_in,
                              void* d_out, int out_size, void* d_ws, size_t ws_size,
                              hipStream_t stream){
  const float* x_enc  = (const float*)d_in[0];
  const float* conv_w = (const float*)d_in[2];
  const float* prompt = (const float*)d_in[3];
  const float* wpe    = (const float*)d_in[4];
  const float* ln1_g  = (const float*)d_in[5];
  const float* ln1_b  = (const float*)d_in[6];
  const float* attn_w = (const float*)d_in[7];
  const float* attn_b = (const float*)d_in[8];
  const float* proj_w = (const float*)d_in[9];
  const float* proj_b = (const float*)d_in[10];
  const float* ln2_g  = (const float*)d_in[11];
  const float* ln2_b  = (const float*)d_in[12];
  const float* fc1_w  = (const float*)d_in[13];
  const float* fc1_b  = (const float*)d_in[14];
  const float* fc2_w  = (const float*)d_in[15];
  const float* fc2_b  = (const float*)d_in[16];
  const float* lnf_g  = (const float*)d_in[17];
  const float* lnf_b  = (const float*)d_in[18];
  const float* ll1_w  = (const float*)d_in[19];
  const float* ll1_b  = (const float*)d_in[20];
  const float* ll0_w  = (const float*)d_in[21];
  const float* ll0_b  = (const float*)d_in[22];
  const float* l2s_w  = (const float*)d_in[23];
  const float* l2s_b  = (const float*)d_in[24];
  const float* w_l2s  = (const float*)d_in[25];
  const float* lnp_g  = (const float*)d_in[26];
  const float* lnp_b  = (const float*)d_in[27];
  const float* out_w  = (const float*)d_in[28];
  const float* out_b  = (const float*)d_in[29];
  const int*   eidx   = (const int*)d_in[30];
  const int*   eseg   = (const int*)d_in[31];
  float* out = (float*)d_out;

  float* ws = (float*)d_ws;
  const size_t SZ_H = (size_t)NTOKz * Dz;            // 6,881,280
  float* h0   = ws;
  float* hbuf = ws + SZ_H;
  float* xb   = ws + 2 * SZ_H;
  float* h2   = ws + 3 * SZ_H;
  float* qkv  = ws + 4 * SZ_H;                       // 20,643,840
  float* big  = qkv + (size_t)NTOKz * 3 * Dz;        // 27,525,120 (mlp mid)
  float* pe   = big + (size_t)NTOKz * DMLPz;
  float* cwt  = pe + (size_t)LENS * Dz;
  float* sbuf = cwt + 144 * Dz;
  float* Pbuf = sbuf + Bz * Dz;
  float* nrm  = Pbuf + Bz * Dz;
  float* cosb = nrm + NTOKz;
  float* ewb  = cosb + Bz * EPBz;
  float* stat = ewb + Bz * EPBz;                     // 128 floats
  unsigned short* WT = (unsigned short*)(stat + 128);  // bf16-split weights, 9.44 MB

  // ---- phase A: encoder + graph weights + l2s precompute ----
  k_pe    <<<(LENS * Dz) / 256, 256, 0, stream>>>(pe);
  k_cwt   <<<(144 * Dz) / 256, 256, 0, stream>>>(conv_w, cwt);
  k_conv  <<<Bz * LENS, 256, 0, stream>>>(x_enc, cwt, pe, h0);
  k_prompt<<<(Bz * LENP * Dz) / 256, 256, 0, stream>>>(prompt, h0);
  k_norms <<<NTOKz, 64, 0, stream>>>(h0, nrm);
  k_ecos  <<<Bz * EPBz, 64, 0, stream>>>(h0, eidx, nrm, cosb);
  k_esoft <<<Bz, 256, 0, stream>>>(cosb, eseg, ewb);
  k_fills <<<(Bz * Dz) / 256, 256, 0, stream>>>(ll1_b, ll0_b, sbuf);
  k_splitk<<<dim3(Dz / 64, 96), 256, 0, stream>>>(h0, 0,     ll1_w, sbuf, KBIGz,  1024);
  k_splitk<<<dim3(Dz / 64, 9),  256, 0, stream>>>(h0, KBIGz, ll0_w, sbuf, KSMALLz, 1024);
  k_psmall<<<(Bz * Dz) / 256, 256, 0, stream>>>(sbuf, l2s_w, Pbuf);
  k_addwpe<<<(int)(SZ_H / 256), 256, 0, stream>>>(h0, wpe, hbuf);

  // ---- phase B: 6 transformer layers ----
  for (int l = 0; l < NLz; ++l){
    k_ln<<<NTOKz, 256, 0, stream>>>(hbuf, xb, ln1_g + l * Dz, ln1_b + l * Dz);

    k_wt<<<dim3(3 * Dz / 64, Dz / 64), 256, 0, stream>>>(
        attn_w + (size_t)l * Dz * 3 * Dz, WT, Dz, 3 * Dz);
    k_bgemm<0><<<dim3(3 * Dz / 128, NTOKz / 128), 256, 0, stream>>>(
        xb, WT, attn_b + l * 3 * Dz, nullptr, qkv,
        NTOKz, 3 * Dz, Dz, nullptr, nullptr, nullptr, 0.f);

    k_attn2<<<Bz * NHz, 512, 0, stream>>>(qkv, xb);

    k_wt<<<dim3(Dz / 64, Dz / 64), 256, 0, stream>>>(
        proj_w + (size_t)l * Dz * Dz, WT, Dz, Dz);
    k_bgemm<1><<<dim3(Dz / 128, NTOKz / 128), 256, 0, stream>>>(
        xb, WT, proj_b + l * Dz, hbuf, h2,
        NTOKz, Dz, Dz, nullptr, nullptr, nullptr, 0.f);

    k_gnn<<<(int)(SZ_H / 256), 256, 0, stream>>>(h2, ewb, hbuf);
    k_ln<<<NTOKz, 256, 0, stream>>>(hbuf, xb, ln2_g + l * Dz, ln2_b + l * Dz);

    k_wt<<<dim3(DMLPz / 64, Dz / 64), 256, 0, stream>>>(
        fc1_w + (size_t)l * Dz * DMLPz, WT, Dz, DMLPz);
    k_bgemm<2><<<dim3(DMLPz / 128, NTOKz / 128), 256, 0, stream>>>(
        xb, WT, fc1_b + l * DMLPz, nullptr, big,
        NTOKz, DMLPz, Dz, nullptr, nullptr, nullptr, 0.f);

    k_wt<<<dim3(Dz / 64, DMLPz / 64), 256, 0, stream>>>(
        fc2_w + (size_t)l * DMLPz * Dz, WT, DMLPz, Dz);
    k_bgemm<3><<<dim3(Dz / 128, NTOKz / 128), 256, 0, stream>>>(
        big, WT, fc2_b + l * Dz, hbuf, hbuf,
        NTOKz, Dz, DMLPz, Pbuf, l2s_b, w_l2s, (float)(1 << l));
  }

  // ---- phase C: final LN + gelu + big LN + head ----
  k_lnfgelu<<<NTOKz, 256, 0, stream>>>(hbuf, xb, lnf_g, lnf_b);
  k_zstats <<<Bz, 256, 0, stream>>>(xb, stat);
  k_head   <<<Bz, 256, 0, stream>>>(xb, stat, lnp_g, lnp_b, out_w, out_b, out);
}

// Round 5
// 4724.521 us; speedup vs baseline: 1.4196x; 1.0278x over previous
//
#include <hip/hip_runtime.h>
#include <math.h>

// ---------------- problem constants ----------------
#define Bz     64
#define LENS   128
#define LENP   12
#define Tz     140
#define Dz     768
#define NHz    12
#define HDz    64
#define NLz    6
#define DMLPz  3072
#define NCLSz  10
#define EPBz   278                 // edges per batch = 2*(T-1)
#define NTOKz  (Bz*Tz)             // 8960
#define ZDIMz  (Tz*Dz)             // 107520
#define KBIGz  (LENS*Dz)           // 98304
#define KSMALLz (LENP*Dz)          // 9216
#define PSTR   168                 // attn P/V panel stride in ushorts

typedef float f32x4 __attribute__((ext_vector_type(4)));
typedef unsigned int u32x4 __attribute__((ext_vector_type(4)));
typedef short short8 __attribute__((ext_vector_type(8)));

__device__ __forceinline__ float wave_sum(float v){
  #pragma unroll
  for (int m = 32; m; m >>= 1) v += __shfl_xor(v, m);
  return v;
}
__device__ __forceinline__ float red16_max(float v){
  v = fmaxf(v, __shfl_xor(v, 1));
  v = fmaxf(v, __shfl_xor(v, 2));
  v = fmaxf(v, __shfl_xor(v, 4));
  v = fmaxf(v, __shfl_xor(v, 8));
  return v;
}
__device__ __forceinline__ float red16_sum(float v){
  v += __shfl_xor(v, 1); v += __shfl_xor(v, 2);
  v += __shfl_xor(v, 4); v += __shfl_xor(v, 8);
  return v;
}
__device__ __forceinline__ float gelu_tanh(float u){
  float c = 0.7978845608028654f * (u + 0.044715f * u * u * u);
  return 0.5f * u * (1.0f + tanhf(c));
}
__device__ __forceinline__ float gelu_exact(float u){
  return 0.5f * u * (1.0f + erff(u * 0.7071067811865476f));
}

// float -> bf16 (RNE) and back
__device__ __forceinline__ unsigned int f2bf(float x){
  unsigned int u = __float_as_uint(x);
  return (u + 0x7fffu + ((u >> 16) & 1u)) >> 16;
}
__device__ __forceinline__ float bf2f(unsigned int h){
  return __uint_as_float(h << 16);
}

// v_mfma_f32_16x16x32_bf16 via inline asm (verified in k_bgemm)
__device__ __forceinline__ f32x4 mfma_bf16(u32x4 a, u32x4 b, f32x4 c){
  asm("v_mfma_f32_16x16x32_bf16 %0, %1, %2, %0" : "+v"(c) : "v"(a), "v"(b));
  return c;
}
// builtin MFMA (hazard-safe) for k_attn2 (verified round 4)
__device__ __forceinline__ short8 pun(u32x4 u){
  union { u32x4 u; short8 s; } x; x.u = u; return x.s;
}
__device__ __forceinline__ f32x4 mfma_b(u32x4 a, u32x4 b, f32x4 c){
  return __builtin_amdgcn_mfma_f32_16x16x32_bf16(pun(a), pun(b), c, 0, 0, 0);
}

// async global->LDS 16B copy (per-lane global src, wave-linear LDS dest)
__device__ __forceinline__ void gl_lds16(const void* g, void* l){
  __builtin_amdgcn_global_load_lds(
      (const __attribute__((address_space(1))) unsigned int*)g,
      (__attribute__((address_space(3))) unsigned int*)l, 16, 0, 0);
}

// 8 consecutive fp32 -> bf16 hi/lo packed operands
__device__ __forceinline__ void cvt_hilo(f32x4 x0, f32x4 x1, u32x4& h, u32x4& l){
  unsigned int h0 = f2bf(x0[0]), h1 = f2bf(x0[1]), h2 = f2bf(x0[2]), h3 = f2bf(x0[3]);
  unsigned int h4 = f2bf(x1[0]), h5 = f2bf(x1[1]), h6 = f2bf(x1[2]), h7 = f2bf(x1[3]);
  unsigned int l0 = f2bf(x0[0] - bf2f(h0)), l1 = f2bf(x0[1] - bf2f(h1));
  unsigned int l2 = f2bf(x0[2] - bf2f(h2)), l3 = f2bf(x0[3] - bf2f(h3));
  unsigned int l4 = f2bf(x1[0] - bf2f(h4)), l5 = f2bf(x1[1] - bf2f(h5));
  unsigned int l6 = f2bf(x1[2] - bf2f(h6)), l7 = f2bf(x1[3] - bf2f(h7));
  h[0] = h0 | (h1 << 16); h[1] = h2 | (h3 << 16);
  h[2] = h4 | (h5 << 16); h[3] = h6 | (h7 << 16);
  l[0] = l0 | (l1 << 16); l[1] = l2 | (l3 << 16);
  l[2] = l4 | (l5 << 16); l[3] = l6 | (l7 << 16);
}

// XT swizzle: 16B-chunk C of a row r is stored at (C&~7) | ((C&7)^(r&7)).
// Matches the k_bgemm LDS fragment layout (16B-granular XOR within 128B window).
__device__ __forceinline__ int swz_chunk(int C, int r){
  return (C & ~7) | ((C & 7) ^ (r & 7));
}

// ---------------- positional encoding (once) ----------------
__global__ void k_pe(float* pe){
  int idx = blockIdx.x * 256 + threadIdx.x;      // < 128*768
  int s = idx / Dz, o = idx % Dz;
  int ie = o & ~1;
  double ang = (double)s * pow(10000.0, -(double)ie / (double)Dz);
  pe[idx] = (o & 1) ? (float)cos(ang) : (float)sin(ang);
}

// transpose conv_w (768,48,3) -> cwt[(k*48+i)*768 + o]
__global__ void k_cwt(const float* __restrict__ cw, float* __restrict__ cwt){
  int idx = blockIdx.x * 256 + threadIdx.x;      // < 144*768
  int o = idx % Dz, j = idx / Dz;                // j = k*48+i
  int i = j % 48, k = j / 48;
  cwt[j * Dz + o] = cw[o * 144 + i * 3 + k];
}

// conv encoder: one block per (b,s); h0[b,s,:] = conv + PE
__global__ __launch_bounds__(256) void k_conv(const float* __restrict__ x_enc,
                                              const float* __restrict__ cwt,
                                              const float* __restrict__ pe,
                                              float* __restrict__ h0){
  int b = blockIdx.x / LENS, s = blockIdx.x % LENS;
  int tid = threadIdx.x;
  __shared__ float in144[144];
  if (tid < 144){
    int k = tid / 48, i = tid % 48;
    int sp = (s + k - 1 + LENS) % LENS;
    int p = i / 3, m = i % 3;
    int j = sp * 8 + p; if (j > 1023) j = 1023;
    in144[tid] = x_enc[(b * 1024 + j) * 3 + m];
  }
  __syncthreads();
  for (int o = tid; o < Dz; o += 256){
    float acc = pe[s * Dz + o];
    #pragma unroll 8
    for (int j = 0; j < 144; ++j) acc += in144[j] * cwt[j * Dz + o];
    h0[((size_t)(b * Tz + s)) * Dz + o] = acc;
  }
}

__global__ void k_prompt(const float* __restrict__ pr, float* __restrict__ h0){
  int idx = blockIdx.x * 256 + threadIdx.x;      // < 64*12*768
  int b = idx / (LENP * Dz), r = idx % (LENP * Dz);
  h0[((size_t)(b * Tz + LENS)) * Dz + r] = pr[r];
}

// node L2 norms (one wave per node)
__global__ void k_norms(const float* __restrict__ h0, float* __restrict__ nrm){
  int n = blockIdx.x, lane = threadIdx.x;
  const float* r = h0 + (size_t)n * Dz;
  float s = 0.f;
  for (int d = lane; d < Dz; d += 64){ float v = r[d]; s += v * v; }
  s = wave_sum(s);
  if (lane == 0) nrm[n] = sqrtf(s);
}

// per-edge cosine (one wave per edge)
__global__ void k_ecos(const float* __restrict__ h0, const int* __restrict__ eidx,
                       const float* __restrict__ nrm, float* __restrict__ cosb){
  int e = blockIdx.x, lane = threadIdx.x;
  int sN = eidx[e], dN = eidx[Bz * EPBz + e];
  const float* a = h0 + (size_t)sN * Dz;
  const float* b = h0 + (size_t)dN * Dz;
  float s = 0.f;
  for (int d = lane; d < Dz; d += 64) s += a[d] * b[d];
  s = wave_sum(s);
  if (lane == 0) cosb[e] = s / (nrm[sN] * nrm[dN] + 1e-8f);
}

// segment softmax (2 segments per batch), one block per batch
__global__ __launch_bounds__(256) void k_esoft(const float* __restrict__ cosb,
                                               const int* __restrict__ eseg,
                                               float* __restrict__ ew){
  int b = blockIdx.x, tid = threadIdx.x;
  __shared__ float c[EPBz];
  __shared__ unsigned char gg[EPBz];
  __shared__ float r0[256], r1[256];
  for (int e = tid; e < EPBz; e += 256){
    c[e] = cosb[b * EPBz + e];
    gg[e] = (unsigned char)(eseg[b * EPBz + e] - 2 * b);
  }
  __syncthreads();
  float m0 = -1e30f, m1 = -1e30f;
  for (int e = tid; e < EPBz; e += 256){
    if (gg[e]) m1 = fmaxf(m1, c[e]); else m0 = fmaxf(m0, c[e]);
  }
  r0[tid] = m0; r1[tid] = m1; __syncthreads();
  for (int s = 128; s; s >>= 1){
    if (tid < s){ r0[tid] = fmaxf(r0[tid], r0[tid+s]); r1[tid] = fmaxf(r1[tid], r1[tid+s]); }
    __syncthreads();
  }
  m0 = r0[0]; m1 = r1[0]; __syncthreads();
  float s0 = 0.f, s1 = 0.f;
  for (int e = tid; e < EPBz; e += 256){
    float ex = expf(c[e] - (gg[e] ? m1 : m0));
    c[e] = ex;
    if (gg[e]) s1 += ex; else s0 += ex;
  }
  r0[tid] = s0; r1[tid] = s1; __syncthreads();
  for (int s = 128; s; s >>= 1){
    if (tid < s){ r0[tid] += r0[tid+s]; r1[tid] += r1[tid+s]; }
    __syncthreads();
  }
  s0 = r0[0]; s1 = r1[0];
  for (int e = tid; e < EPBz; e += 256)
    ew[b * EPBz + e] = c[e] / ((gg[e] ? s1 : s0) + 1e-8f);
}

// s init with both biases
__global__ void k_fills(const float* __restrict__ b1, const float* __restrict__ b0,
                        float* __restrict__ sbuf){
  int idx = blockIdx.x * 256 + threadIdx.x;      // < 64*768
  int d = idx % Dz;
  sbuf[idx] = b1[d] + b0[d];
}

// split-K GEMM: C(64x768) += A(64 x K) @ W(K x 768); A rows stride ZDIM in h0.
// Round 5: float4 loads + register double-buffer prefetch.
__global__ __launch_bounds__(256) void k_splitk(const float* __restrict__ Abase, int aOff,
                                                const float* __restrict__ W,
                                                float* __restrict__ Cacc,
                                                int K, int kChunk){
  __shared__ __align__(16) float As[16 * 65];
  __shared__ __align__(16) float Ws[16 * 64];
  int tid = threadIdx.x, tx = tid % 16, ty = tid / 16;
  int n0 = blockIdx.x * 64;
  int kb = blockIdx.y * kChunk;
  int ke = kb + kChunk; if (ke > K) ke = K;
  float acc[16];
  #pragma unroll
  for (int i = 0; i < 16; ++i) acc[i] = 0.f;
  int mA = tid >> 2, kqA = (tid & 3) * 4;        // A: 64 rows x 16 k, float4 along k
  int nB = (tid * 4) & 63, kB = tid >> 4;        // W: 16 k x 64 n, float4 along n
  f32x4 ra = *(const f32x4*)&Abase[(size_t)mA * ZDIMz + aOff + kb + kqA];
  f32x4 rw = *(const f32x4*)&W[(size_t)(kb + kB) * Dz + n0 + nB];
  for (int kk = kb; kk < ke; kk += 16){
    As[(kqA + 0) * 65 + mA] = ra[0];
    As[(kqA + 1) * 65 + mA] = ra[1];
    As[(kqA + 2) * 65 + mA] = ra[2];
    As[(kqA + 3) * 65 + mA] = ra[3];
    *(f32x4*)&Ws[kB * 64 + nB] = rw;
    __syncthreads();
    if (kk + 16 < ke){
      ra = *(const f32x4*)&Abase[(size_t)mA * ZDIMz + aOff + kk + 16 + kqA];
      rw = *(const f32x4*)&W[(size_t)(kk + 16 + kB) * Dz + n0 + nB];
    }
    #pragma unroll
    for (int k = 0; k < 16; ++k){
      float a[4], bvv[4];
      #pragma unroll
      for (int i = 0; i < 4; ++i) a[i] = As[k * 65 + ty * 4 + i];
      #pragma unroll
      for (int j = 0; j < 4; ++j) bvv[j] = Ws[k * 64 + tx * 4 + j];
      #pragma unroll
      for (int i = 0; i < 4; ++i)
        #pragma unroll
        for (int j = 0; j < 4; ++j) acc[i * 4 + j] += a[i] * bvv[j];
    }
    __syncthreads();
  }
  #pragma unroll
  for (int i = 0; i < 4; ++i)
    #pragma unroll
    for (int j = 0; j < 4; ++j)
      atomicAdd(&Cacc[(size_t)(ty * 4 + i) * Dz + n0 + tx * 4 + j], acc[i * 4 + j]);
}

// P[b,d] = sum_{c<128} s[b,c]*l2s_w[c,d]
__global__ void k_psmall(const float* __restrict__ sbuf, const float* __restrict__ l2sw,
                         float* __restrict__ P){
  int idx = blockIdx.x * 256 + threadIdx.x;      // < 64*768
  int b = idx / Dz, d = idx % Dz;
  float acc = 0.f;
  #pragma unroll 8
  for (int c = 0; c < 128; ++c) acc += sbuf[b * Dz + c] * l2sw[c * Dz + d];
  P[idx] = acc;
}

__global__ void k_addwpe(const float* __restrict__ h0, const float* __restrict__ wpe,
                         float* __restrict__ h){
  size_t idx = (size_t)blockIdx.x * 256 + threadIdx.x;   // < NTOK*D
  int n = (int)(idx / Dz), d = (int)(idx % Dz);
  int t = n % Tz;
  h[idx] = h0[idx] + wpe[t * Dz + d];
}

// layernorm writing pre-split bf16 hi/lo XT (swizzled) — feeds k_bgemm AFMT=1.
__global__ __launch_bounds__(256) void k_lnx(const float* __restrict__ in,
                                             unsigned short* __restrict__ XA,
                                             const float* __restrict__ g,
                                             const float* __restrict__ bb){
  int row = blockIdx.x, tid = threadIdx.x;
  const float* r = in + (size_t)row * Dz;
  __shared__ float buf[768];
  __shared__ float red[256];
  float v0 = r[tid], v1 = r[tid + 256], v2 = r[tid + 512];
  buf[tid] = v0; buf[tid + 256] = v1; buf[tid + 512] = v2;
  red[tid] = v0 + v1 + v2; __syncthreads();
  for (int s = 128; s; s >>= 1){ if (tid < s) red[tid] += red[tid + s]; __syncthreads(); }
  float mu = red[0] * (1.0f / Dz); __syncthreads();
  float d0 = v0 - mu, d1 = v1 - mu, d2 = v2 - mu;
  red[tid] = d0 * d0 + d1 * d1 + d2 * d2; __syncthreads();
  for (int s = 128; s; s >>= 1){ if (tid < s) red[tid] += red[tid + s]; __syncthreads(); }
  float rstd = rsqrtf(red[0] * (1.0f / Dz) + 1e-5f);
  if (tid < 96){
    int kg = tid;
    f32x4 g0 = *(const f32x4*)&g[kg * 8],  g1 = *(const f32x4*)&g[kg * 8 + 4];
    f32x4 b0 = *(const f32x4*)&bb[kg * 8], b1 = *(const f32x4*)&bb[kg * 8 + 4];
    f32x4 x0, x1;
    #pragma unroll
    for (int j = 0; j < 4; ++j) x0[j] = (buf[kg * 8 + j]     - mu) * rstd * g0[j] + b0[j];
    #pragma unroll
    for (int j = 0; j < 4; ++j) x1[j] = (buf[kg * 8 + 4 + j] - mu) * rstd * g1[j] + b1[j];
    u32x4 hv, lv;
    cvt_hilo(x0, x1, hv, lv);
    size_t rb = (size_t)row * 1536;              // 2*Dz ushorts per row
    *(u32x4*)&XA[rb + swz_chunk(kg * 2,     row) * 8] = hv;
    *(u32x4*)&XA[rb + swz_chunk(kg * 2 + 1, row) * 8] = lv;
  }
}

// ---------------------------------------------------------------------------
// weight transpose+split: W[K][N] fp32 -> WT[N][...] bf16 hi/lo, PRE-SWIZZLED
// so k_bgemm can stage with linear global_load_lds.
// ---------------------------------------------------------------------------
__global__ __launch_bounds__(256) void k_wt(const float* __restrict__ W,
                                            unsigned short* __restrict__ WT,
                                            int K, int N){
  __shared__ float T[64][65];
  int k0 = blockIdx.y * 64, n0v = blockIdx.x * 64;
  int tid = threadIdx.x;
  int tx = tid & 15, ty = tid >> 4;
  #pragma unroll
  for (int rr = 0; rr < 4; ++rr){
    int row = rr * 16 + ty;
    const float* src = &W[(size_t)(k0 + row) * N + n0v + tx * 4];
    f32x4 v = *(const f32x4*)src;
    T[row][tx * 4]     = v[0];
    T[row][tx * 4 + 1] = v[1];
    T[row][tx * 4 + 2] = v[2];
    T[row][tx * 4 + 3] = v[3];
  }
  __syncthreads();
  #pragma unroll
  for (int s = 0; s < 2; ++s){
    int gi = tid + s * 256;                      // 64 n x 8 k-groups
    int n = gi >> 3, kg = gi & 7;
    unsigned int h[8], l[8];
    #pragma unroll
    for (int j = 0; j < 8; ++j){
      float x = T[kg * 8 + j][n];
      h[j] = f2bf(x);
      l[j] = f2bf(x - bf2f(h[j]));
    }
    u32x4 hv, lv;
    hv[0] = h[0] | (h[1] << 16); hv[1] = h[2] | (h[3] << 16);
    hv[2] = h[4] | (h[5] << 16); hv[3] = h[6] | (h[7] << 16);
    lv[0] = l[0] | (l[1] << 16); lv[1] = l[2] | (l[3] << 16);
    lv[2] = l[4] | (l[5] << 16); lv[3] = l[6] | (l[7] << 16);
    int r = n0v + n;
    int C0 = (k0 / 8 + kg) * 2;
    size_t rb = (size_t)r * 2 * K;
    *(u32x4*)&WT[rb + swz_chunk(C0,     r) * 8] = hv;
    *(u32x4*)&WT[rb + swz_chunk(C0 + 1, r) * 8] = lv;
  }
}

// ---------------------------------------------------------------------------
// bf16x2-split MFMA GEMM. AFMT=1: A pre-split in AX (XT layout) -> staged with
// global_load_lds (linear dest, pre-swizzled src). AFMT=0: A fp32, cvt in-loop
// (fc2 path). B always staged from pre-swizzled WT via global_load_lds.
// Fragment reads + MFMA + epilogue unchanged from the verified kernel.
// ---------------------------------------------------------------------------
template<int MODE, int AFMT>
__global__ __launch_bounds__(256, 2) void k_bgemm(const float* __restrict__ A,
                                                  const unsigned short* __restrict__ AX,
                                                  const unsigned short* __restrict__ WT,
                                                  const float* __restrict__ bias,
                                                  const float* __restrict__ R,
                                                  float* __restrict__ C, int M, int N, int K,
                                                  const float* __restrict__ P,
                                                  const float* __restrict__ l2sb,
                                                  const float* __restrict__ wl2s, float lscale){
  __shared__ __align__(16) unsigned short As[128 * 64];
  __shared__ __align__(16) unsigned short Bs[128 * 64];
  int tid = threadIdx.x;
  int n0 = blockIdx.x * 128, m0 = blockIdx.y * 128;
  int w = tid >> 6, lane = tid & 63;
  int wr = w >> 1, wc = w & 1;
  int g = lane >> 4, q = lane & 15;

  f32x4 acc[4][4];
  #pragma unroll
  for (int i = 0; i < 4; ++i)
    #pragma unroll
    for (int j = 0; j < 4; ++j) acc[i][j] = (f32x4){0.f, 0.f, 0.f, 0.f};

  const size_t rbytes = (size_t)K * 4;           // XT row bytes (2K ushorts)

  for (int kk = 0; kk < K; kk += 32){
    if (AFMT == 1){
      #pragma unroll
      for (int s = 0; s < 4; ++s){
        int i16 = tid + s * 256;                 // wave-contiguous 16B chunk id
        int m = i16 >> 3, cc = i16 & 7;
        const char* src = (const char*)AX + (size_t)(m0 + m) * rbytes + (size_t)kk * 4 + cc * 16;
        gl_lds16(src, (char*)As + (size_t)i16 * 16);
      }
    } else {
      #pragma unroll
      for (int s = 0; s < 2; ++s){
        int gi = tid + s * 256;
        int m = gi >> 2, kb2 = gi & 3;
        const float* src = A + (size_t)(m0 + m) * K + kk + kb2 * 8;
        f32x4 x0 = *(const f32x4*)src;
        f32x4 x1 = *(const f32x4*)(src + 4);
        u32x4 hv, lv;
        cvt_hilo(x0, x1, hv, lv);
        int sw = (m & 7) << 3;
        unsigned short* rp = &As[m * 64];
        *(u32x4*)&rp[(kb2 * 16) ^ sw]     = hv;
        *(u32x4*)&rp[(kb2 * 16 + 8) ^ sw] = lv;
      }
    }
    #pragma unroll
    for (int s = 0; s < 4; ++s){
      int i16 = tid + s * 256;
      int n = i16 >> 3, cc = i16 & 7;
      const char* src = (const char*)WT + (size_t)(n0 + n) * rbytes + (size_t)kk * 4 + cc * 16;
      gl_lds16(src, (char*)Bs + (size_t)i16 * 16);
    }
    __syncthreads();

    u32x4 aH[4], aL[4], bH[4], bL[4];
    #pragma unroll
    for (int f = 0; f < 4; ++f){
      int row = wr * 64 + f * 16 + q;
      int swa = (row & 7) << 3;
      const unsigned short* rp = &As[row * 64];
      aH[f] = *(const u32x4*)&rp[(g * 16) ^ swa];
      aL[f] = *(const u32x4*)&rp[(g * 16 + 8) ^ swa];
      int col = wc * 64 + f * 16 + q;
      int swb = (col & 7) << 3;
      const unsigned short* cp = &Bs[col * 64];
      bH[f] = *(const u32x4*)&cp[(g * 16) ^ swb];
      bL[f] = *(const u32x4*)&cp[(g * 16 + 8) ^ swb];
    }
    #pragma unroll
    for (int i = 0; i < 4; ++i)
      #pragma unroll
      for (int j = 0; j < 4; ++j){
        acc[i][j] = mfma_bf16(aH[i], bH[j], acc[i][j]);
        acc[i][j] = mfma_bf16(aH[i], bL[j], acc[i][j]);
        acc[i][j] = mfma_bf16(aL[i], bH[j], acc[i][j]);
      }
    __syncthreads();
  }

  float wv = 0.f;
  if (MODE == 3) wv = wl2s[0];
  #pragma unroll
  for (int i = 0; i < 4; ++i){
    #pragma unroll
    for (int r = 0; r < 4; ++r){
      int row = m0 + wr * 64 + i * 16 + g * 4 + r;
      int b = row / Tz, t = row % Tz;
      float ct = (t < LENS) ? (1.0f / LENS) : (1.0f / LENP);
      #pragma unroll
      for (int j = 0; j < 4; ++j){
        int col = n0 + wc * 64 + j * 16 + q;
        size_t idx = (size_t)row * N + col;
        float v = acc[i][j][r] + bias[col];
        if (MODE == 1) v += R[idx];
        if (MODE == 2) v = gelu_tanh(v);
        if (MODE == 3){
          v += R[idx];
          v += wv * ct * (lscale * P[b * Dz + col] + l2sb[col]);
        }
        C[idx] = v;
      }
    }
  }
}

// ---------------------------------------------------------------------------
// MFMA flash attention (verified round 4) — epilogue now writes XT (pre-split
// bf16 hi/lo, swizzled) via an LDS repack reusing the free P panel, so proj's
// GEMM can stage it with global_load_lds.
// ---------------------------------------------------------------------------
__global__ __launch_bounds__(512, 1) void k_attn2(const float* __restrict__ qkv,
                                                  unsigned short* __restrict__ XA){
  int bh = blockIdx.x; int b = bh / NHz, hh = bh % NHz;
  int tid = threadIdx.x, w = tid >> 6, lane = tid & 63;
  int g = lane >> 4, q = lane & 15;

  __shared__ __align__(16) unsigned short Vb[64 * PSTR];      // 21504 B
  __shared__ __align__(16) unsigned short Pp[8][16 * PSTR];   // 43008 B

  const float* base = qkv + (size_t)b * Tz * (3 * Dz) + hh * HDz;

  // ---- stage Vb[d][j] = bf16(V[j][d]); zero cols j in [140,160) ----
  for (int e = tid; e < 64 * 160; e += 512){
    int d = e / 160, j = e - d * 160;
    float v = (j < Tz) ? base[(size_t)j * (3 * Dz) + 2 * Dz + d] : 0.f;
    Vb[d * PSTR + j] = (unsigned short)f2bf(v);
  }
  __syncthreads();

  unsigned short* Pw = &Pp[w][0];

  for (int tile = w; tile < 9; tile += 8){
    int i0 = tile * 16;

    // ---- Q A-frags direct from global ----
    u32x4 qh[2], ql[2];
    {
      int row = i0 + q; if (row > Tz - 1) row = Tz - 1;
      const float* qp = base + (size_t)row * (3 * Dz);
      #pragma unroll
      for (int kt = 0; kt < 2; ++kt){
        f32x4 x0 = *(const f32x4*)(qp + kt * 32 + g * 8);
        f32x4 x1 = *(const f32x4*)(qp + kt * 32 + g * 8 + 4);
        cvt_hilo(x0, x1, qh[kt], ql[kt]);
      }
    }

    // ---- S = Q K^T over col-tiles 0..tile (causal skip), bf16x2 ----
    f32x4 acc[9];
    #pragma unroll
    for (int j = 0; j < 9; ++j) acc[j] = (f32x4){0.f, 0.f, 0.f, 0.f};
    #pragma unroll
    for (int j = 0; j < 9; ++j){
      if (j > tile) continue;
      int col = j * 16 + q; if (col > Tz - 1) col = Tz - 1;
      const float* kp = base + (size_t)col * (3 * Dz) + Dz;
      #pragma unroll
      for (int kt = 0; kt < 2; ++kt){
        f32x4 x0 = *(const f32x4*)(kp + kt * 32 + g * 8);
        f32x4 x1 = *(const f32x4*)(kp + kt * 32 + g * 8 + 4);
        u32x4 kh, kl;
        cvt_hilo(x0, x1, kh, kl);
        acc[j] = mfma_b(qh[kt], kh, acc[j]);
        acc[j] = mfma_b(qh[kt], kl, acc[j]);
        acc[j] = mfma_b(ql[kt], kh, acc[j]);
      }
    }

    // ---- row softmax ----
    #pragma unroll
    for (int r = 0; r < 4; ++r){
      int t = i0 + g * 4 + r;
      float mx = -1e30f;
      #pragma unroll
      for (int j = 0; j < 9; ++j){
        if (j > tile) continue;
        int col = j * 16 + q;
        float s = acc[j][r] * 0.125f;
        bool valid = (col <= t) && (col < Tz);
        s = valid ? s : -1e30f;
        acc[j][r] = s;
        mx = fmaxf(mx, s);
      }
      mx = red16_max(mx);
      float sum = 0.f;
      #pragma unroll
      for (int j = 0; j < 9; ++j){
        if (j > tile) continue;
        float e = expf(acc[j][r] - mx);
        acc[j][r] = e;
        sum += e;
      }
      sum = red16_sum(sum);
      float inv = 1.0f / sum;
      #pragma unroll
      for (int j = 0; j < 9; ++j){
        if (j > tile) continue;
        acc[j][r] *= inv;
      }
    }

    // ---- write FULL P panel (bf16): rows 0..15 x cols 0..159 ----
    #pragma unroll
    for (int j = 0; j < 10; ++j){
      const int jc = (j < 9) ? j : 0;
      #pragma unroll
      for (int r = 0; r < 4; ++r){
        float p = (j < 9 && j <= tile) ? acc[jc][r] : 0.f;
        Pw[(g * 4 + r) * PSTR + j * 16 + q] = (unsigned short)f2bf(p);
      }
    }
    __builtin_amdgcn_sched_barrier(0);
    asm volatile("s_waitcnt lgkmcnt(0)" ::: "memory");
    __builtin_amdgcn_sched_barrier(0);

    // ---- O = P V (single-bf16, 1 MFMA per step) ----
    f32x4 oacc[4];
    #pragma unroll
    for (int dt = 0; dt < 4; ++dt) oacc[dt] = (f32x4){0.f, 0.f, 0.f, 0.f};
    #pragma unroll
    for (int kt = 0; kt < 5; ++kt){
      if (kt > (tile >> 1)) continue;
      u32x4 pa = *(const u32x4*)&Pw[q * PSTR + kt * 32 + g * 8];
      #pragma unroll
      for (int dt = 0; dt < 4; ++dt){
        u32x4 vv = *(const u32x4*)&Vb[(dt * 16 + q) * PSTR + kt * 32 + g * 8];
        oacc[dt] = mfma_b(pa, vv, oacc[dt]);
      }
    }

    // ---- repack oacc -> XT via per-wave LDS scratch (reuses Pw, 4KB) ----
    float* Pf = (float*)Pw;
    __builtin_amdgcn_sched_barrier(0);
    asm volatile("s_waitcnt lgkmcnt(0)" ::: "memory");   // PV reads done
    __builtin_amdgcn_sched_barrier(0);
    #pragma unroll
    for (int r = 0; r < 4; ++r)
      #pragma unroll
      for (int dt = 0; dt < 4; ++dt)
        Pf[(g * 4 + r) * 64 + dt * 16 + q] = oacc[dt][r];
    __builtin_amdgcn_sched_barrier(0);
    asm volatile("s_waitcnt lgkmcnt(0)" ::: "memory");
    __builtin_amdgcn_sched_barrier(0);
    #pragma unroll
    for (int s = 0; s < 2; ++s){
      int gi = lane + s * 64;                    // 16 rows x 8 groups
      int r16 = gi >> 3, kg8 = gi & 7;
      int t = i0 + r16;
      if (t < Tz){
        int m = b * Tz + t;
        f32x4 x0, x1;
        #pragma unroll
        for (int j = 0; j < 4; ++j) x0[j] = Pf[r16 * 64 + kg8 * 8 + j];
        #pragma unroll
        for (int j = 0; j < 4; ++j) x1[j] = Pf[r16 * 64 + kg8 * 8 + 4 + j];
        u32x4 hv, lv;
        cvt_hilo(x0, x1, hv, lv);
        int C0 = (hh * 8 + kg8) * 2;
        size_t rb = (size_t)m * 1536;
        *(u32x4*)&XA[rb + swz_chunk(C0,     m) * 8] = hv;
        *(u32x4*)&XA[rb + swz_chunk(C0 + 1, m) * 8] = lv;
      }
    }
    __builtin_amdgcn_sched_barrier(0);
    asm volatile("s_waitcnt lgkmcnt(0)" ::: "memory");   // reads done before next tile reuses Pw
    __builtin_amdgcn_sched_barrier(0);
  }
}

// chain-graph aggregation: h = h2 + ew_l*h2[t-1] + ew_r*h2[t+1]
__global__ void k_gnn(const float* __restrict__ h2, const float* __restrict__ ew,
                      float* __restrict__ h){
  size_t idx = (size_t)blockIdx.x * 256 + threadIdx.x;   // < NTOK*D
  int n = (int)(idx / Dz);
  int b = n / Tz, t = n % Tz;
  float v = h2[idx];
  if (t >= 1)      v += ew[b * EPBz + 2 * (t - 1)]     * h2[idx - Dz];
  if (t <= Tz - 2) v += ew[b * EPBz + 2 * t + 1]       * h2[idx + Dz];
  h[idx] = v;
}

// final LN + exact gelu
__global__ __launch_bounds__(256) void k_lnfgelu(const float* __restrict__ in, float* __restrict__ out,
                                                 const float* __restrict__ g, const float* __restrict__ bb){
  int row = blockIdx.x, tid = threadIdx.x;
  const float* r = in + (size_t)row * Dz;
  float v0 = r[tid], v1 = r[tid + 256], v2 = r[tid + 512];
  __shared__ float red[256];
  red[tid] = v0 + v1 + v2; __syncthreads();
  for (int s = 128; s; s >>= 1){ if (tid < s) red[tid] += red[tid + s]; __syncthreads(); }
  float mu = red[0] * (1.0f / Dz); __syncthreads();
  float d0 = v0 - mu, d1 = v1 - mu, d2 = v2 - mu;
  red[tid] = d0 * d0 + d1 * d1 + d2 * d2; __syncthreads();
  for (int s = 128; s; s >>= 1){ if (tid < s) red[tid] += red[tid + s]; __syncthreads(); }
  float rstd = rsqrtf(red[0] * (1.0f / Dz) + 1e-5f);
  float* o = out + (size_t)row * Dz;
  o[tid]       = gelu_exact(d0 * rstd * g[tid]       + bb[tid]);
  o[tid + 256] = gelu_exact(d1 * rstd * g[tid + 256] + bb[tid + 256]);
  o[tid + 512] = gelu_exact(d2 * rstd * g[tid + 512] + bb[tid + 512]);
}

// per-batch stats over ZDIM (fp64 accumulation)
__global__ __launch_bounds__(256) void k_zstats(const float* __restrict__ z, float* __restrict__ stat){
  int b = blockIdx.x, tid = threadIdx.x;
  const float* zr = z + (size_t)b * ZDIMz;
  double s = 0.0, qq = 0.0;
  for (int k = tid; k < ZDIMz; k += 256){ double v = zr[k]; s += v; qq += v * v; }
  __shared__ double rs_[256], rq_[256];
  rs_[tid] = s; rq_[tid] = qq; __syncthreads();
  for (int st = 128; st; st >>= 1){
    if (tid < st){ rs_[tid] += rs_[tid + st]; rq_[tid] += rq_[tid + st]; }
    __syncthreads();
  }
  if (tid == 0){
    double mu = rs_[0] / ZDIMz;
    double var = rq_[0] / ZDIMz - mu * mu;
    stat[b] = (float)mu;
    stat[64 + b] = (float)(1.0 / sqrt(var + 1e-5));
  }
}

// head: out[b,:] = LN(z_b)*g+b  @ out_w + out_b
__global__ __launch_bounds__(256) void k_head(const float* __restrict__ z, const float* __restrict__ stat,
                                              const float* __restrict__ lg, const float* __restrict__ lb,
                                              const float* __restrict__ W, const float* __restrict__ ob,
                                              float* __restrict__ out){
  int b = blockIdx.x, tid = threadIdx.x;
  float mu = stat[b], rs = stat[64 + b];
  const float* zr = z + (size_t)b * ZDIMz;
  float acc[NCLSz];
  #pragma unroll
  for (int j = 0; j < NCLSz; ++j) acc[j] = 0.f;
  for (int k = tid; k < ZDIMz; k += 256){
    float v = (zr[k] - mu) * rs * lg[k] + lb[k];
    const float* wr = W + (size_t)k * NCLSz;
    #pragma unroll
    for (int j = 0; j < NCLSz; ++j) acc[j] += v * wr[j];
  }
  __shared__ float red[256];
  for (int j = 0; j < NCLSz; ++j){
    red[tid] = acc[j]; __syncthreads();
    for (int s = 128; s; s >>= 1){ if (tid < s) red[tid] += red[tid + s]; __syncthreads(); }
    if (tid == 0) out[b * NCLSz + j] = red[0] + ob[j];
    __syncthreads();
  }
}

extern "C" void kernel_launch(void* const* d_in, const int* in_sizes, int n_in,
                              void* d_out, int out_size, void* d_ws, size_t ws_size,
                              hipStream_t stream){
  const float* x_enc  = (const float*)d_in[0];
  const float* conv_w = (const float*)d_in[2];
  const float* prompt = (const float*)d_in[3];
  const float* wpe    = (const float*)d_in[4];
  const float* ln1_g  = (const float*)d_in[5];
  const float* ln1_b  = (const float*)d_in[6];
  const float* attn_w = (const float*)d_in[7];
  const float* attn_b = (const float*)d_in[8];
  const float* proj_w = (const float*)d_in[9];
  const float* proj_b = (const float*)d_in[10];
  const float* ln2_g  = (const float*)d_in[11];
  const float* ln2_b  = (const float*)d_in[12];
  const float* fc1_w  = (const float*)d_in[13];
  const float* fc1_b  = (const float*)d_in[14];
  const float* fc2_w  = (const float*)d_in[15];
  const float* fc2_b  = (const float*)d_in[16];
  const float* lnf_g  = (const float*)d_in[17];
  const float* lnf_b  = (const float*)d_in[18];
  const float* ll1_w  = (const float*)d_in[19];
  const float* ll1_b  = (const float*)d_in[20];
  const float* ll0_w  = (const float*)d_in[21];
  const float* ll0_b  = (const float*)d_in[22];
  const float* l2s_w  = (const float*)d_in[23];
  const float* l2s_b  = (const float*)d_in[24];
  const float* w_l2s  = (const float*)d_in[25];
  const float* lnp_g  = (const float*)d_in[26];
  const float* lnp_b  = (const float*)d_in[27];
  const float* out_w  = (const float*)d_in[28];
  const float* out_b  = (const float*)d_in[29];
  const int*   eidx   = (const int*)d_in[30];
  const int*   eseg   = (const int*)d_in[31];
  float* out = (float*)d_out;

  float* ws = (float*)d_ws;
  const size_t SZ_H = (size_t)NTOKz * Dz;            // 6,881,280
  float* h0   = ws;
  float* hbuf = ws + SZ_H;
  float* xb   = ws + 2 * SZ_H;                       // phase C fp32; phase B: XA alias
  float* h2   = ws + 3 * SZ_H;
  float* qkv  = ws + 4 * SZ_H;                       // 20,643,840
  float* big  = qkv + (size_t)NTOKz * 3 * Dz;        // 27,525,120 (mlp mid)
  float* pe   = big + (size_t)NTOKz * DMLPz;
  float* cwt  = pe + (size_t)LENS * Dz;
  float* sbuf = cwt + 144 * Dz;
  float* Pbuf = sbuf + Bz * Dz;
  float* nrm  = Pbuf + Bz * Dz;
  float* cosb = nrm + NTOKz;
  float* ewb  = cosb + Bz * EPBz;
  float* stat = ewb + Bz * EPBz;                     // 128 floats
  unsigned short* WT = (unsigned short*)(stat + 128);  // bf16-split weights, 9.44 MB
  unsigned short* XA = (unsigned short*)xb;            // pre-split activations (aliases xb)

  // ---- phase A ----
  k_pe    <<<(LENS * Dz) / 256, 256, 0, stream>>>(pe);
  k_cwt   <<<(144 * Dz) / 256, 256, 0, stream>>>(conv_w, cwt);
  k_conv  <<<Bz * LENS, 256, 0, stream>>>(x_enc, cwt, pe, h0);
  k_prompt<<<(Bz * LENP * Dz) / 256, 256, 0, stream>>>(prompt, h0);
  k_norms <<<NTOKz, 64, 0, stream>>>(h0, nrm);
  k_ecos  <<<Bz * EPBz, 64, 0, stream>>>(h0, eidx, nrm, cosb);
  k_esoft <<<Bz, 256, 0, stream>>>(cosb, eseg, ewb);
  k_fills <<<(Bz * Dz) / 256, 256, 0, stream>>>(ll1_b, ll0_b, sbuf);
  k_splitk<<<dim3(Dz / 64, KBIGz / 512), 256, 0, stream>>>(h0, 0,     ll1_w, sbuf, KBIGz,  512);
  k_splitk<<<dim3(Dz / 64, KSMALLz / 512), 256, 0, stream>>>(h0, KBIGz, ll0_w, sbuf, KSMALLz, 512);
  k_psmall<<<(Bz * Dz) / 256, 256, 0, stream>>>(sbuf, l2s_w, Pbuf);
  k_addwpe<<<(int)(SZ_H / 256), 256, 0, stream>>>(h0, wpe, hbuf);

  // ---- phase B: 6 transformer layers ----
  for (int l = 0; l < NLz; ++l){
    k_lnx<<<NTOKz, 256, 0, stream>>>(hbuf, XA, ln1_g + l * Dz, ln1_b + l * Dz);

    k_wt<<<dim3(3 * Dz / 64, Dz / 64), 256, 0, stream>>>(
        attn_w + (size_t)l * Dz * 3 * Dz, WT, Dz, 3 * Dz);
    k_bgemm<0, 1><<<dim3(3 * Dz / 128, NTOKz / 128), 256, 0, stream>>>(
        nullptr, XA, WT, attn_b + l * 3 * Dz, nullptr, qkv,
        NTOKz, 3 * Dz, Dz, nullptr, nullptr, nullptr, 0.f);

    k_attn2<<<Bz * NHz, 512, 0, stream>>>(qkv, XA);

    k_wt<<<dim3(Dz / 64, Dz / 64), 256, 0, stream>>>(
        proj_w + (size_t)l * Dz * Dz, WT, Dz, Dz);
    k_bgemm<1, 1><<<dim3(Dz / 128, NTOKz / 128), 256, 0, stream>>>(
        nullptr, XA, WT, proj_b + l * Dz, hbuf, h2,
        NTOKz, Dz, Dz, nullptr, nullptr, nullptr, 0.f);

    k_gnn<<<(int)(SZ_H / 256), 256, 0, stream>>>(h2, ewb, hbuf);
    k_lnx<<<NTOKz, 256, 0, stream>>>(hbuf, XA, ln2_g + l * Dz, ln2_b + l * Dz);

    k_wt<<<dim3(DMLPz / 64, Dz / 64), 256, 0, stream>>>(
        fc1_w + (size_t)l * Dz * DMLPz, WT, Dz, DMLPz);
    k_bgemm<2, 1><<<dim3(DMLPz / 128, NTOKz / 128), 256, 0, stream>>>(
        nullptr, XA, WT, fc1_b + l * DMLPz, nullptr, big,
        NTOKz, DMLPz, Dz, nullptr, nullptr, nullptr, 0.f);

    k_wt<<<dim3(Dz / 64, DMLPz / 64), 256, 0, stream>>>(
        fc2_w + (size_t)l * DMLPz * Dz, WT, DMLPz, Dz);
    k_bgemm<3, 0><<<dim3(Dz / 128, NTOKz / 128), 256, 0, stream>>>(
        big, nullptr, WT, fc2_b + l * Dz, hbuf, hbuf,
        NTOKz, Dz, DMLPz, Pbuf, l2s_b, w_l2s, (float)(1 << l));
  }

  // ---- phase C ----
  k_lnfgelu<<<NTOKz, 256, 0, stream>>>(hbuf, xb, lnf_g, lnf_b);
  k_zstats <<<Bz, 256, 0, stream>>>(xb, stat);
  k_head   <<<Bz, 256, 0, stream>>>(xb, stat, lnp_g, lnp_b, out_w, out_b, out);
}